// Round 8
// baseline (337.264 us; speedup 1.0000x reference)
//
#include <hip/hip_runtime.h>
#include <math.h>

namespace {
constexpr int BB = 32, NPG = 4096, NTOT = BB*NPG, C = 128, FIN = 64, KK = 32, JJ = 40;
constexpr int YROWS = BB*JJ; // 1280
constexpr float EPS = 1e-5f;

// CW (precomputed folded constants) float offsets
constexpr int CW_WU  = 0;      // [64][32] Wu[d][k] = sum_c W[c][d]*U[c][k]
constexpr int CW_WV  = 2048;   // [64][32] Wv[d][k] = sum_c W[c][d]*V[c][k]
constexpr int CW_VU  = 4096;   // [32][32] VU[k'][k] = sum_c V[c][k']*U[c][k]
constexpr int CW_WG  = 5120;   // [64]     sum_c W[c][d]*gw[c]
constexpr int CW_VGX = 5184;   // [32]     sum_c V[c][k]*gw[c]
constexpr int CW_VGH = 5216;   // [32]     sum_c V[c][k]*gw[128+c]
constexpr int CW_CBU = 5248;   // [32]     sum_c b[c]*U[c][k]
constexpr int CW_CSU = 5280;   // [32]     sum_c U[c][k]
constexpr int CW_CBV = 5312;   // [32]     sum_c b[c]*V[c][k]
constexpr int CW_CSV = 5344;   // [32]     sum_c V[c][k]
constexpr int CW_SC  = 5376;   // bG = b.gw[0:128], sG = sum gw[0:128]
constexpr int CW_G   = 5384;   // [64][64] G[d][e] = sum_c W[c][d]*W[c][e]
constexpr int CW_WB  = 9480;   // [64]     wb[d] = sum_c W[c][d]*b[c]
constexpr int CW_SW  = 9544;   // [64]     sw[d] = sum_c W[c][d]
constexpr int CW_SB  = 9608;   // sb = sum b, sb2 = sum b^2
constexpr int CW_SIZE = 9610;

// workspace layout (float offsets), all fp32 except ST/PB (double)
constexpr size_t XU_OFF  = 0;                               // NTOT*32
constexpr size_t GX_OFF  = XU_OFF + (size_t)NTOT*KK;        // NTOT
constexpr size_t YP_OFF  = GX_OFF + (size_t)NTOT;           // 1280*32
constexpr size_t PMA_OFF = YP_OFF + (size_t)YROWS*KK;       // 32*40*64
constexpr size_t PSA_OFF = PMA_OFF + 81920;
constexpr size_t PMB_OFF = PSA_OFF + 81920;
constexpr size_t PSB_OFF = PMB_OFF + 81920;
constexpr size_t CWS_OFF = PSB_OFF + 81920;
constexpr size_t PBN_OFF = CWS_OFF + 9612;                  // 512 double-pairs (nf)
constexpr size_t PBF_OFF = PBN_OFF + 2048;                  // 20 double-pairs (fe)
constexpr size_t MS_OFF  = PBF_OFF + 80;                    // 32*80 (M,Si per graph)
constexpr size_t ST_OFF  = MS_OFF + 2560;                   // 4 doubles
}

#define ACC8(A, wv, u0, u1) do { \
  A[0] += (wv)*(u0).x; A[1] += (wv)*(u0).y; A[2] += (wv)*(u0).z; A[3] += (wv)*(u0).w; \
  A[4] += (wv)*(u1).x; A[5] += (wv)*(u1).y; A[6] += (wv)*(u1).z; A[7] += (wv)*(u1).w; } while(0)

__device__ __forceinline__ float dot4(const float4 a, const float4 b) {
  return a.x*b.x + a.y*b.y + a.z*b.z + a.w*b.w;
}
__device__ __forceinline__ float dot8v(const float x[8], const float4 y0, const float4 y1) {
  return x[0]*y0.x + x[1]*y0.y + x[2]*y0.z + x[3]*y0.w
       + x[4]*y1.x + x[5]*y1.y + x[6]*y1.z + x[7]*y1.w;
}
__device__ __forceinline__ float sigm(const float x) { return 1.f/(1.f + __expf(-x)); }

// ---------------------------------------------------------------------------
// K0: fold W/U/V/gate into small matrices. Block 0: WU/WV/VU/gate folds.
// Block 1: G = W^T W, wb, sw, sb/sb2.   (unchanged, proven)
// ---------------------------------------------------------------------------
__global__ __launch_bounds__(256)
void k_pre(const float* __restrict__ W, const float* __restrict__ b,
           const float* __restrict__ U, const float* __restrict__ V,
           const float* __restrict__ gw, float* __restrict__ CWo) {
  __shared__ float W_l[128*64];
  __shared__ float V_l[128*32];
  const int t = threadIdx.x;
  for (int f = t; f < 2048; f += 256) *(float4*)(W_l + 4*f) = *(const float4*)(W + 4*f);
  if (blockIdx.x == 0)
    for (int f = t; f < 1024; f += 256) *(float4*)(V_l + 4*f) = *(const float4*)(V + 4*f);
  __syncthreads();
  if (blockIdx.x == 1) {
    const int d = t >> 2, e0 = (t & 3) * 16;
    float g[16];
    #pragma unroll
    for (int i = 0; i < 16; ++i) g[i] = 0.f;
    for (int c = 0; c < 128; ++c) {
      const float wv = W_l[c*64 + d];
      #pragma unroll
      for (int u = 0; u < 4; ++u) {
        const float4 we = *(const float4*)(W_l + c*64 + e0 + 4*u);
        g[4*u+0] += wv*we.x; g[4*u+1] += wv*we.y;
        g[4*u+2] += wv*we.z; g[4*u+3] += wv*we.w;
      }
    }
    #pragma unroll
    for (int u = 0; u < 4; ++u)
      *(float4*)(CWo + CW_G + d*64 + e0 + 4*u) = make_float4(g[4*u],g[4*u+1],g[4*u+2],g[4*u+3]);
    if (t < 64) {
      float awb = 0.f, asw = 0.f;
      for (int c = 0; c < 128; ++c) {
        const float wv = W_l[c*64 + t];
        awb += wv * b[c]; asw += wv;
      }
      CWo[CW_WB + t] = awb; CWo[CW_SW + t] = asw;
    }
    if (t == 0) {
      float sb = 0.f, sb2 = 0.f;
      for (int c = 0; c < 128; ++c) { sb += b[c]; sb2 += b[c]*b[c]; }
      CWo[CW_SB+0] = sb; CWo[CW_SB+1] = sb2;
    }
    return;
  }
  {
    const int d = t >> 2, k0 = (t & 3) * 8;
    float au[8] = {0,0,0,0,0,0,0,0};
    float av[8] = {0,0,0,0,0,0,0,0};
    for (int c = 0; c < 128; ++c) {
      const float wv = W_l[c*64 + d];
      const float4 u0 = *(const float4*)(U + c*32 + k0);
      const float4 u1 = *(const float4*)(U + c*32 + k0 + 4);
      ACC8(au, wv, u0, u1);
      const float4 v0 = *(const float4*)(V_l + c*32 + k0);
      const float4 v1 = *(const float4*)(V_l + c*32 + k0 + 4);
      ACC8(av, wv, v0, v1);
    }
    *(float4*)(CWo + CW_WU + d*32 + k0)     = make_float4(au[0],au[1],au[2],au[3]);
    *(float4*)(CWo + CW_WU + d*32 + k0 + 4) = make_float4(au[4],au[5],au[6],au[7]);
    *(float4*)(CWo + CW_WV + d*32 + k0)     = make_float4(av[0],av[1],av[2],av[3]);
    *(float4*)(CWo + CW_WV + d*32 + k0 + 4) = make_float4(av[4],av[5],av[6],av[7]);
  }
  if (t < 128) {
    const int kp = t >> 2, k0 = (t & 3) * 8;
    float a[8] = {0,0,0,0,0,0,0,0};
    for (int c = 0; c < 128; ++c) {
      const float vv = V_l[c*32 + kp];
      const float4 u0 = *(const float4*)(U + c*32 + k0);
      const float4 u1 = *(const float4*)(U + c*32 + k0 + 4);
      ACC8(a, vv, u0, u1);
    }
    *(float4*)(CWo + CW_VU + kp*32 + k0)     = make_float4(a[0],a[1],a[2],a[3]);
    *(float4*)(CWo + CW_VU + kp*32 + k0 + 4) = make_float4(a[4],a[5],a[6],a[7]);
  }
  if (t < 64) {
    float a = 0.f;
    for (int c = 0; c < 128; ++c) a += W_l[c*64 + t] * gw[c];
    CWo[CW_WG + t] = a;
  }
  if (t < 32) {
    float a1=0,a2=0,a3=0,a4=0,a5=0,a6=0;
    for (int c = 0; c < 128; ++c) {
      const float uv = U[c*32 + t], vv = V_l[c*32 + t], bc = b[c];
      a1 += vv*gw[c]; a2 += vv*gw[128+c];
      a3 += bc*uv;    a4 += uv;
      a5 += bc*vv;    a6 += vv;
    }
    CWo[CW_VGX+t]=a1; CWo[CW_VGH+t]=a2; CWo[CW_CBU+t]=a3; CWo[CW_CSU+t]=a4;
    CWo[CW_CBV+t]=a5; CWo[CW_CSV+t]=a6;
  }
  if (t == 0) {
    float bg=0.f, sg=0.f;
    for (int c = 0; c < 128; ++c) { bg += b[c]*gw[c]; sg += gw[c]; }
    CWo[CW_SC+0]=bg; CWo[CW_SC+1]=sg;
  }
}

// ---------------------------------------------------------------------------
// K1: stats via second moments (unchanged, proven). Per-block pair to PB.
// ---------------------------------------------------------------------------
__global__ __launch_bounds__(256,6)
void k_cov(const float* __restrict__ inp, const float* __restrict__ CW,
           double* __restrict__ PB, const int ntiles) {
  __shared__ float a_l[64*64];
  __shared__ float red[12];
  const int t = threadIdx.x;
  const int dg = t >> 4, eg = t & 15;
  const int d0 = dg*4, e0 = eg*4;
  float av1 = 0.f, av2 = 0.f, avb = 0.f;
  int nt = 0;
  for (int tile = blockIdx.x; tile < ntiles; tile += gridDim.x) {
    __syncthreads();
    const size_t r0 = (size_t)tile * 64;
    #pragma unroll
    for (int s = 0; s < 4; ++s) {
      int f = (t + 256*s) * 4;
      *(float4*)(a_l + f) = *(const float4*)(inp + r0*FIN + f);
    }
    __syncthreads();
    float S[4][4];
    #pragma unroll
    for (int i=0;i<4;i++)
      #pragma unroll
      for (int j=0;j<4;j++) S[i][j] = 0.f;
    float4 cs = make_float4(0.f,0.f,0.f,0.f);
    #pragma unroll 4
    for (int r = 0; r < 64; ++r) {
      const float4 ad = *(const float4*)(a_l + r*64 + d0);
      const float4 ae = *(const float4*)(a_l + r*64 + e0);
      S[0][0]+=ad.x*ae.x; S[0][1]+=ad.x*ae.y; S[0][2]+=ad.x*ae.z; S[0][3]+=ad.x*ae.w;
      S[1][0]+=ad.y*ae.x; S[1][1]+=ad.y*ae.y; S[1][2]+=ad.y*ae.z; S[1][3]+=ad.y*ae.w;
      S[2][0]+=ad.z*ae.x; S[2][1]+=ad.z*ae.y; S[2][2]+=ad.z*ae.z; S[2][3]+=ad.z*ae.w;
      S[3][0]+=ad.w*ae.x; S[3][1]+=ad.w*ae.y; S[3][2]+=ad.w*ae.z; S[3][3]+=ad.w*ae.w;
      cs.x += ad.x; cs.y += ad.y; cs.z += ad.z; cs.w += ad.w;
    }
    #pragma unroll
    for (int i = 0; i < 4; ++i) {
      const float4 g4 = *(const float4*)(CW + CW_G + (d0+i)*64 + e0);
      av2 += S[i][0]*g4.x + S[i][1]*g4.y + S[i][2]*g4.z + S[i][3]*g4.w;
    }
    if (eg == 0) {
      const float4 sw4 = *(const float4*)(CW + CW_SW + d0);
      const float4 wb4 = *(const float4*)(CW + CW_WB + d0);
      av1 += cs.x*sw4.x + cs.y*sw4.y + cs.z*sw4.z + cs.w*sw4.w;
      avb += cs.x*wb4.x + cs.y*wb4.y + cs.z*wb4.z + cs.w*wb4.w;
    }
    ++nt;
  }
  #pragma unroll
  for (int off = 32; off > 0; off >>= 1) {
    av2 += __shfl_xor(av2, off);
    av1 += __shfl_xor(av1, off);
    avb += __shfl_xor(avb, off);
  }
  const int w = t >> 6;
  if ((t & 63) == 0) { red[w*3] = av1; red[w*3+1] = av2; red[w*3+2] = avb; }
  __syncthreads();
  if (t == 0) {
    const float sb = CW[CW_SB], sb2 = CW[CW_SB+1];
    const double rowsB = 64.0 * (double)nt;
    const double s1 = (double)(red[0]+red[3]+red[6]+red[9]);
    const double s2 = (double)(red[1]+red[4]+red[7]+red[10]);
    const double sB = (double)(red[2]+red[5]+red[8]+red[11]);
    PB[(size_t)blockIdx.x*2 + 0] = s1 + rowsB*(double)sb;
    PB[(size_t)blockIdx.x*2 + 1] = s2 + 2.0*sB + rowsB*(double)sb2;
  }
}

// ---------------------------------------------------------------------------
// K1b: combine per-block double-pairs into ST[0..3]. One block.
// ---------------------------------------------------------------------------
__global__ __launch_bounds__(256)
void k_comb(const double* __restrict__ PBn, const double* __restrict__ PBf,
            double* __restrict__ ST) {
  __shared__ double red[8];
  const int t = threadIdx.x;
  double a = PBn[2*t] + PBn[2*(t+256)];
  double b = PBn[2*t+1] + PBn[2*(t+256)+1];
  #pragma unroll
  for (int off = 32; off > 0; off >>= 1) {
    a += __shfl_down(a, off);
    b += __shfl_down(b, off);
  }
  if ((t & 63) == 0) { red[(t>>6)*2] = a; red[(t>>6)*2+1] = b; }
  __syncthreads();
  if (t == 0) {
    ST[0] = red[0]+red[2]+red[4]+red[6];
    ST[1] = red[1]+red[3]+red[5]+red[7];
  }
  if (t < 64) {
    double c = (t < 20) ? PBf[2*t]   : 0.0;
    double d = (t < 20) ? PBf[2*t+1] : 0.0;
    #pragma unroll
    for (int off = 32; off > 0; off >>= 1) {
      c += __shfl_down(c, off);
      d += __shfl_down(d, off);
    }
    if (t == 0) { ST[2] = c; ST[3] = d; }
  }
}

// ---------------------------------------------------------------------------
// K1c: combine softmax partials (Pm/Ps 64-wide) into per-(b,j) M, 1/S.
// grid = 32 (one block per graph).
// ---------------------------------------------------------------------------
__global__ __launch_bounds__(256)
void k_comb2(const float* __restrict__ Pm, const float* __restrict__ Ps,
             float* __restrict__ MS) {
  __shared__ float Mq[160], Sq[160], Msh[40];
  const int t = threadIdx.x;
  const int b = blockIdx.x;
  const int j = t >> 2, q = t & 3;
  float pm[16];
  if (t < 160) {
    float m = 0.f;
    #pragma unroll
    for (int u = 0; u < 16; ++u) {
      pm[u] = Pm[(size_t)b*2560 + j*64 + q*16 + u];
      m = fmaxf(m, pm[u]);
    }
    Mq[t] = m;
  }
  __syncthreads();
  if (t < 40) Msh[t] = fmaxf(fmaxf(Mq[4*t], Mq[4*t+1]), fmaxf(Mq[4*t+2], Mq[4*t+3]));
  __syncthreads();
  if (t < 160) {
    const float M = Msh[j];
    float s = 0.f;
    #pragma unroll
    for (int u = 0; u < 16; ++u)
      s += Ps[(size_t)b*2560 + j*64 + q*16 + u] * __expf(pm[u] - M);
    Sq[t] = s;
  }
  __syncthreads();
  if (t < 40) {
    const float S = Sq[4*t] + Sq[4*t+1] + Sq[4*t+2] + Sq[4*t+3];
    MS[(size_t)b*80 + t] = Msh[t];
    MS[(size_t)b*80 + 40 + t] = 1.f/S;
  }
}

// ---------------------------------------------------------------------------
// partials_lds: softmax partials from p staged in LDS (stride 44). Proven.
// ---------------------------------------------------------------------------
__device__ __forceinline__ void partials_lds(const float* p_l, const int t,
    float* sredm, float* sreds, float* redm,
    float* __restrict__ PmB, float* __restrict__ PsB) {
  const int r2 = t >> 2, kq = t & 3;
  const int w = t >> 6, tl = t & 63;
  float ev[10];
  #pragma unroll
  for (int m = 0; m < 10; ++m) ev[m] = p_l[r2*44 + 4*m + kq];
  float mv[10];
  #pragma unroll
  for (int m = 0; m < 10; ++m) {
    mv[m] = ev[m];
    mv[m] = fmaxf(mv[m], __shfl_xor(mv[m], 4));
    mv[m] = fmaxf(mv[m], __shfl_xor(mv[m], 8));
    mv[m] = fmaxf(mv[m], __shfl_xor(mv[m], 16));
    mv[m] = fmaxf(mv[m], __shfl_xor(mv[m], 32));
  }
  if (tl < 4) {
    #pragma unroll
    for (int m = 0; m < 10; ++m) sredm[w*40 + 4*m + kq] = mv[m];
  }
  __syncthreads();
  if (t < 40)
    redm[t] = fmaxf(fmaxf(sredm[t], sredm[40+t]), fmaxf(sredm[80+t], sredm[120+t]));
  __syncthreads();
  float es[10];
  #pragma unroll
  for (int m = 0; m < 10; ++m) {
    const float M = redm[4*m + kq];
    es[m] = __expf(ev[m]-M);
    es[m] += __shfl_xor(es[m], 4);
    es[m] += __shfl_xor(es[m], 8);
    es[m] += __shfl_xor(es[m], 16);
    es[m] += __shfl_xor(es[m], 32);
  }
  if (tl < 4) {
    #pragma unroll
    for (int m = 0; m < 10; ++m) sreds[w*40 + 4*m + kq] = es[m];
  }
  __syncthreads();
  if (t < 40) {
    PmB[(size_t)t*64] = redm[t];
    PsB[(size_t)t*64] = sreds[t]+sreds[40+t]+sreds[80+t]+sreds[120+t];
  }
}

// ---------------------------------------------------------------------------
// K2: y_p directly from fe (unchanged, proven).
// ---------------------------------------------------------------------------
__global__ __launch_bounds__(256,4)
void k_yp2(const float* __restrict__ fe, const float* __restrict__ CW,
           const float* __restrict__ q, const double* __restrict__ ST,
           float* __restrict__ yp) {
  __shared__ float in_t[64*64];
  __shared__ float Wl[64*32];
  const int t = threadIdx.x;
  const int r0 = blockIdx.x * 64;
  #pragma unroll
  for (int s = 0; s < 4; ++s) {
    int f = (t + 256*s) * 4;
    int r = f >> 6, d = f & 63;
    float4 v = *(const float4*)(fe + (size_t)r0*FIN + f);
    *(float4*)(in_t + r*64 + (d ^ ((r & 7) * 8))) = v;
  }
  #pragma unroll
  for (int s = 0; s < 2; ++s) {
    int f = (t + 256*s) * 4;
    *(float4*)(Wl + f) = *(const float4*)(CW + CW_WV + f);
  }
  __syncthreads();
  const double cy = (double)YROWS * (double)C;
  const double myd = ST[2]/cy, vy = ST[3]/cy - myd*myd;
  const float ry = (float)(1.0/sqrt(vy + (double)EPS));
  const float mr = (float)myd * ry;
  const int r2 = t >> 2, kq = t & 3;
  const int swz = (r2 & 7) * 8;
  float acc[8] = {0,0,0,0,0,0,0,0};
  #pragma unroll
  for (int dc = 0; dc < 16; ++dc) {
    const int d = dc*4;
    const float4 a = *(const float4*)(in_t + r2*64 + (d ^ swz));
    { const float4 w0 = *(const float4*)(Wl + (d+0)*32 + kq*8);
      const float4 w1 = *(const float4*)(Wl + (d+0)*32 + kq*8 + 4); ACC8(acc, a.x, w0, w1); }
    { const float4 w0 = *(const float4*)(Wl + (d+1)*32 + kq*8);
      const float4 w1 = *(const float4*)(Wl + (d+1)*32 + kq*8 + 4); ACC8(acc, a.y, w0, w1); }
    { const float4 w0 = *(const float4*)(Wl + (d+2)*32 + kq*8);
      const float4 w1 = *(const float4*)(Wl + (d+2)*32 + kq*8 + 4); ACC8(acc, a.z, w0, w1); }
    { const float4 w0 = *(const float4*)(Wl + (d+3)*32 + kq*8);
      const float4 w1 = *(const float4*)(Wl + (d+3)*32 + kq*8 + 4); ACC8(acc, a.w, w0, w1); }
  }
  #pragma unroll
  for (int i = 0; i < 8; ++i) {
    const int k = kq*8 + i;
    const float typ = ry*(acc[i] + CW[CW_CBV+k]) - mr*CW[CW_CSV+k];
    float v = fmaxf(typ, 0.f);
    acc[i] = fmaxf(q[k]*v, 0.f);
  }
  *(float4*)(yp + (size_t)(r0+r2)*KK + kq*8)     = make_float4(acc[0],acc[1],acc[2],acc[3]);
  *(float4*)(yp + (size_t)(r0+r2)*KK + kq*8 + 4) = make_float4(acc[4],acc[5],acc[6],acc[7]);
}

// ---------------------------------------------------------------------------
// K3: layer-0, 4-row register-blocked; I-row STREAMED to p_l (kills p[4][10]).
// ---------------------------------------------------------------------------
__global__ __launch_bounds__(256,4)
void k_I0b(const float* __restrict__ nf, const float* __restrict__ CW,
           const double* __restrict__ ST, const float* __restrict__ yp,
           float* __restrict__ XU, float* __restrict__ GX,
           float* __restrict__ Pm, float* __restrict__ Ps) {
  __shared__ __align__(16) float in_t[64*68];   // overlaid by p_l (64*44) later
  __shared__ __align__(16) float Wl[64*36];     // row d -> (d&15)*4 + (d>>4)
  __shared__ __align__(16) float ypj[40*40];
  __shared__ __align__(16) float wgl[64];
  __shared__ float sredm[160], sreds[160], redm[40];
  float* p_l = in_t;
  const int t = threadIdx.x;
  const int bid = blockIdx.x;
  const int b = bid >> 6, blk = bid & 63;
  const size_t rowbase = (size_t)b*NPG + (size_t)blk*64;
  #pragma unroll
  for (int s = 0; s < 4; ++s) {
    int f = (t + 256*s) * 4;
    int r = f >> 6, d = f & 63;
    *(float4*)(in_t + r*68 + d) = *(const float4*)(nf + rowbase*FIN + f);
  }
  #pragma unroll
  for (int s = 0; s < 2; ++s) {
    int idx = t + 256*s;
    int d = idx >> 3, kc = idx & 7;
    *(float4*)(Wl + ((d&15)*4 + (d>>4))*36 + kc*4) = *(const float4*)(CW + CW_WU + idx*4);
  }
  for (int f4v = t; f4v < 320; f4v += 256) {
    int j = f4v >> 3, kc = f4v & 7;
    *(float4*)(ypj + j*40 + kc*4) = *(const float4*)(yp + (size_t)b*(JJ*KK) + f4v*4);
  }
  if (t < 64) wgl[t] = CW[CW_WG + t];
  __syncthreads();
  const double cx = (double)NTOT * (double)C;
  const double mx = ST[0]/cx, vx = ST[1]/cx - mx*mx;
  const float rx = (float)(1.0/sqrt(vx + (double)EPS));
  const float mr = (float)mx * rx;
  const int kq = t & 3, X = (t >> 2) & 3, rr = t >> 4;
  float acc[4][8];
  #pragma unroll
  for (int i=0;i<4;i++)
    #pragma unroll
    for (int u=0;u<8;u++) acc[i][u] = 0.f;
  #pragma unroll
  for (int dd = 0; dd < 4; ++dd) {
    float4 a4[4];
    #pragma unroll
    for (int i = 0; i < 4; ++i)
      a4[i] = *(const float4*)(in_t + (rr+16*i)*68 + X*16 + dd*4);
    #pragma unroll
    for (int qd = 0; qd < 4; ++qd) {
      const int lrow = (dd*4 + qd)*4 + X;
      const float4 w0 = *(const float4*)(Wl + lrow*36 + kq*8);
      const float4 w1 = *(const float4*)(Wl + lrow*36 + kq*8 + 4);
      #pragma unroll
      for (int i = 0; i < 4; ++i) {
        const float av = (qd==0)? a4[i].x : (qd==1)? a4[i].y : (qd==2)? a4[i].z : a4[i].w;
        ACC8(acc[i], av, w0, w1);
      }
    }
  }
  // X-reduce (full 64-d sum)
  #pragma unroll
  for (int i = 0; i < 4; ++i)
    #pragma unroll
    for (int u = 0; u < 8; ++u) {
      acc[i][u] += __shfl_xor(acc[i][u], 4);
      acc[i][u] += __shfl_xor(acc[i][u], 8);
    }
  // gx: d-slice (X*16 + kq*4), reduce over 16 lanes
  float gp[4];
  #pragma unroll
  for (int i = 0; i < 4; ++i) {
    const float4 a = *(const float4*)(in_t + (rr+16*i)*68 + X*16 + kq*4);
    const float4 w = *(const float4*)(wgl + X*16 + kq*4);
    gp[i] = dot4(a, w);
    gp[i] += __shfl_xor(gp[i], 1);
    gp[i] += __shfl_xor(gp[i], 2);
    gp[i] += __shfl_xor(gp[i], 4);
    gp[i] += __shfl_xor(gp[i], 8);
  }
  const float4 cb0 = *(const float4*)(CW + CW_CBU + kq*8);
  const float4 cb1 = *(const float4*)(CW + CW_CBU + kq*8 + 4);
  const float4 cu0 = *(const float4*)(CW + CW_CSU + kq*8);
  const float4 cu1 = *(const float4*)(CW + CW_CSU + kq*8 + 4);
  float xp[4][8];
  #pragma unroll
  for (int i = 0; i < 4; ++i) {
    acc[i][0] = rx*(acc[i][0] + cb0.x) - mr*cu0.x;
    acc[i][1] = rx*(acc[i][1] + cb0.y) - mr*cu0.y;
    acc[i][2] = rx*(acc[i][2] + cb0.z) - mr*cu0.z;
    acc[i][3] = rx*(acc[i][3] + cb0.w) - mr*cu0.w;
    acc[i][4] = rx*(acc[i][4] + cb1.x) - mr*cu1.x;
    acc[i][5] = rx*(acc[i][5] + cb1.y) - mr*cu1.y;
    acc[i][6] = rx*(acc[i][6] + cb1.z) - mr*cu1.z;
    acc[i][7] = rx*(acc[i][7] + cb1.w) - mr*cu1.w;
    #pragma unroll
    for (int u = 0; u < 8; ++u) xp[i][u] = fmaxf(acc[i][u], 0.f);
  }
  if (X == 0) {
    const float bG = CW[CW_SC], sG = CW[CW_SC+1];
    #pragma unroll
    for (int i = 0; i < 4; ++i) {
      const size_t row = rowbase + rr + 16*i;
      *(float4*)(XU + row*KK + kq*8)     = make_float4(acc[i][0],acc[i][1],acc[i][2],acc[i][3]);
      *(float4*)(XU + row*KK + kq*8 + 4) = make_float4(acc[i][4],acc[i][5],acc[i][6],acc[i][7]);
      if (kq == 0) GX[row] = rx*(gp[i] + bG) - mr*sG;
    }
  }
  __syncthreads();                       // all in_t reads done; overlay p_l
  // streamed I-row: per jj compute p4, store scalars (no p[4][10] array)
  #pragma unroll 2
  for (int jj = 0; jj < 10; ++jj) {
    const int j = X*10 + jj;
    const float4 y0 = *(const float4*)(ypj + j*40 + kq*8);
    const float4 y1 = *(const float4*)(ypj + j*40 + kq*8 + 4);
    float p4[4];
    #pragma unroll
    for (int i = 0; i < 4; ++i) p4[i] = dot8v(xp[i], y0, y1);
    #pragma unroll
    for (int i = 0; i < 4; ++i) {
      p4[i] += __shfl_xor(p4[i], 1);
      p4[i] += __shfl_xor(p4[i], 2);
    }
    if (kq == 0) {
      #pragma unroll
      for (int i = 0; i < 4; ++i)
        p_l[(rr+16*i)*44 + j] = p4[i];
    }
  }
  __syncthreads();
  partials_lds(p_l, t, sredm, sreds, redm,
               Pm + (size_t)b*2560 + blk, Ps + (size_t)b*2560 + blk);
}

// ---------------------------------------------------------------------------
// K4: fused layer update, 2-row x 2-pass streaming (spill fix v2):
// live set per pass ~60 VGPR. A+B: per jj -> p2 -> e -> hp2, y read once.
// Then phase C (4-row, unchanged) -> streamed final-I (2-pass) -> partials/out.
// ---------------------------------------------------------------------------
template<int FINAL>
__global__ __launch_bounds__(256)
void k_fused5(float* __restrict__ XU, float* __restrict__ GX,
              const float* __restrict__ yp, const float* __restrict__ CW,
              const float* __restrict__ gb, const float* __restrict__ MS,
              float* __restrict__ PmOut, float* __restrict__ PsOut,
              float* __restrict__ outp) {
  __shared__ __align__(16) float ypj[40*40];
  __shared__ __align__(16) float xp_l[64*36];
  __shared__ __align__(16) float BUF[3456];   // h_l[64*36] | VU_l[32*36]; later p_l[64*44]
  __shared__ __align__(16) float vg_l[64];    // vgx[0:32], vgh[32:64]
  __shared__ float M_l[40], Si_l[40];
  __shared__ float sredm[160], sreds[160], redm[40];
  float* h_l  = BUF;
  float* VU_l = BUF + 2304;
  float* p_l  = BUF;
  const int t = threadIdx.x;
  const int bid = blockIdx.x;
  const int b = bid >> 6, blk = bid & 63;
  const size_t rowbase = (size_t)b*NPG + (size_t)blk*64;
  for (int f4v = t; f4v < 320; f4v += 256) {
    int j = f4v >> 3, kc = f4v & 7;
    *(float4*)(ypj + j*40 + kc*4) = *(const float4*)(yp + (size_t)b*(JJ*KK) + f4v*4);
  }
  { // VU (original orientation [kp][k]) stride 36
    const int d = t >> 3, kc = t & 7;
    *(float4*)(VU_l + d*36 + kc*4) = *(const float4*)(CW + CW_VU + t*4);
  }
  if (t < 32) vg_l[t] = CW[CW_VGX + t];
  else if (t < 64) vg_l[t] = CW[CW_VGH + t - 32];
  if (t < 40) { M_l[t] = MS[(size_t)b*80 + t]; Si_l[t] = MS[(size_t)b*80 + 40 + t]; }
  __syncthreads();
  const int kq = t & 3, jh = (t >> 2) & 3, rr = t >> 4;
  // FUSED A+B: two passes of 2 rows each (live set ~60 VGPR)
  #pragma unroll
  for (int pass = 0; pass < 2; ++pass) {
    const int rb = rr + pass*32;
    float xp2[2][8];
    #pragma unroll
    for (int i = 0; i < 2; ++i) {
      const size_t row = rowbase + rb + 16*i;
      const float4 x0 = *(const float4*)(XU + row*KK + kq*8);
      const float4 x1 = *(const float4*)(XU + row*KK + kq*8 + 4);
      xp2[i][0]=fmaxf(x0.x,0.f); xp2[i][1]=fmaxf(x0.y,0.f);
      xp2[i][2]=fmaxf(x0.z,0.f); xp2[i][3]=fmaxf(x0.w,0.f);
      xp2[i][4]=fmaxf(x1.x,0.f); xp2[i][5]=fmaxf(x1.y,0.f);
      xp2[i][6]=fmaxf(x1.z,0.f); xp2[i][7]=fmaxf(x1.w,0.f);
    }
    float hp2[2][8];
    #pragma unroll
    for (int i=0;i<2;i++)
      #pragma unroll
      for (int u=0;u<8;u++) hp2[i][u] = 0.f;
    #pragma unroll 2
    for (int jj = 0; jj < 10; ++jj) {
      const int j = jh*10 + jj;
      const float4 y0 = *(const float4*)(ypj + j*40 + kq*8);
      const float4 y1 = *(const float4*)(ypj + j*40 + kq*8 + 4);
      float pA = dot8v(xp2[0], y0, y1);
      float pB = dot8v(xp2[1], y0, y1);
      pA += __shfl_xor(pA, 1); pA += __shfl_xor(pA, 2);
      pB += __shfl_xor(pB, 1); pB += __shfl_xor(pB, 2);
      const float Mj = M_l[j], Sj = Si_l[j];
      const float eA = __expf(pA - Mj) * Sj;
      const float eB = __expf(pB - Mj) * Sj;
      ACC8(hp2[0], eA, y0, y1);
      ACC8(hp2[1], eB, y0, y1);
    }
    // jh-reduce -> full j sum
    #pragma unroll
    for (int i = 0; i < 2; ++i)
      #pragma unroll
      for (int u = 0; u < 8; ++u) {
        hp2[i][u] += __shfl_xor(hp2[i][u], 4);
        hp2[i][u] += __shfl_xor(hp2[i][u], 8);
      }
    if (jh == 0) {
      #pragma unroll
      for (int i = 0; i < 2; ++i) {
        const int rl = rb + 16*i;
        *(float4*)(h_l + rl*36 + kq*8) =
          make_float4(fmaxf(hp2[i][0],0.f), fmaxf(hp2[i][1],0.f),
                      fmaxf(hp2[i][2],0.f), fmaxf(hp2[i][3],0.f));
        *(float4*)(h_l + rl*36 + kq*8 + 4) =
          make_float4(fmaxf(hp2[i][4],0.f), fmaxf(hp2[i][5],0.f),
                      fmaxf(hp2[i][6],0.f), fmaxf(hp2[i][7],0.f));
      }
    }
  }
  __syncthreads();
  // phase C: 2 output k per lane, full kp contraction, gate + blend (4-row)
  {
    const int kk2 = t & 15, rr2 = t >> 4;
    float hu0[4] = {0,0,0,0}, hu1[4] = {0,0,0,0};
    float g2[4] = {0,0,0,0}, gxp[4] = {0,0,0,0};
    #pragma unroll
    for (int c8 = 0; c8 < 8; ++c8) {
      const float4 vgx4 = *(const float4*)(vg_l + c8*4);
      const float4 vgh4 = *(const float4*)(vg_l + 32 + c8*4);
      float2 vu[4];
      #pragma unroll
      for (int qd = 0; qd < 4; ++qd)
        vu[qd] = *(const float2*)(VU_l + (c8*4+qd)*36 + kk2*2);
      #pragma unroll
      for (int i = 0; i < 4; ++i) {
        const float4 h4 = *(const float4*)(h_l + (rr2+16*i)*36 + c8*4);
        g2[i]  += dot4(h4, vgh4);
        gxp[i] += dot4(h4, vgx4);
        hu0[i] += h4.x*vu[0].x + h4.y*vu[1].x + h4.z*vu[2].x + h4.w*vu[3].x;
        hu1[i] += h4.x*vu[0].y + h4.y*vu[1].y + h4.z*vu[2].y + h4.w*vu[3].y;
      }
    }
    const float gbv = gb[0];
    #pragma unroll
    for (int i = 0; i < 4; ++i) {
      const size_t row = rowbase + rr2 + 16*i;
      const float gx = GX[row];
      const float2 xu2 = *(const float2*)(XU + row*KK + kk2*2);
      const float z = sigm(gx + g2[i] + gbv);
      const float nx0 = (1.f-z)*xu2.x + z*hu0[i];
      const float nx1 = (1.f-z)*xu2.y + z*hu1[i];
      if (!FINAL) {
        *(float2*)(XU + row*KK + kk2*2) = make_float2(nx0, nx1);
        if (kk2 == 0) GX[row] = (1.f-z)*gx + z*gxp[i];
      }
      *(float2*)(xp_l + (rr2+16*i)*36 + kk2*2) = make_float2(fmaxf(nx0,0.f), fmaxf(nx1,0.f));
    }
  }
  __syncthreads();
  // streamed final-I (2 passes of 2 rows)
  if (FINAL) {
    #pragma unroll
    for (int pass = 0; pass < 2; ++pass) {
      const int rb = rr + pass*32;
      float xp2[2][8];
      #pragma unroll
      for (int i = 0; i < 2; ++i) {
        const int rl = rb + 16*i;
        const float4 x0 = *(const float4*)(xp_l + rl*36 + kq*8);
        const float4 x1 = *(const float4*)(xp_l + rl*36 + kq*8 + 4);
        xp2[i][0]=x0.x; xp2[i][1]=x0.y; xp2[i][2]=x0.z; xp2[i][3]=x0.w;
        xp2[i][4]=x1.x; xp2[i][5]=x1.y; xp2[i][6]=x1.z; xp2[i][7]=x1.w;
      }
      float s2[2] = {0.f, 0.f};
      #pragma unroll 2
      for (int jj = 0; jj < 10; ++jj) {
        const int j = jh*10 + jj;
        const float4 y0 = *(const float4*)(ypj + j*40 + kq*8);
        const float4 y1 = *(const float4*)(ypj + j*40 + kq*8 + 4);
        float pA = dot8v(xp2[0], y0, y1);
        float pB = dot8v(xp2[1], y0, y1);
        pA += __shfl_xor(pA, 1); pA += __shfl_xor(pA, 2);
        pB += __shfl_xor(pB, 1); pB += __shfl_xor(pB, 2);
        s2[0] += pA*pA; s2[1] += pB*pB;
      }
      #pragma unroll
      for (int i = 0; i < 2; ++i) {
        s2[i] += __shfl_xor(s2[i], 4);
        s2[i] += __shfl_xor(s2[i], 8);
      }
      if ((t & 15) == 0) {
        outp[rowbase + rb]      = sigm(s2[0]);
        outp[rowbase + rb + 16] = sigm(s2[1]);
      }
    }
    return;
  }
  #pragma unroll
  for (int pass = 0; pass < 2; ++pass) {
    const int rb = rr + pass*32;
    float xp2[2][8];
    #pragma unroll
    for (int i = 0; i < 2; ++i) {
      const int rl = rb + 16*i;
      const float4 x0 = *(const float4*)(xp_l + rl*36 + kq*8);
      const float4 x1 = *(const float4*)(xp_l + rl*36 + kq*8 + 4);
      xp2[i][0]=x0.x; xp2[i][1]=x0.y; xp2[i][2]=x0.z; xp2[i][3]=x0.w;
      xp2[i][4]=x1.x; xp2[i][5]=x1.y; xp2[i][6]=x1.z; xp2[i][7]=x1.w;
    }
    #pragma unroll 2
    for (int jj = 0; jj < 10; ++jj) {
      const int j = jh*10 + jj;
      const float4 y0 = *(const float4*)(ypj + j*40 + kq*8);
      const float4 y1 = *(const float4*)(ypj + j*40 + kq*8 + 4);
      float pA = dot8v(xp2[0], y0, y1);
      float pB = dot8v(xp2[1], y0, y1);
      pA += __shfl_xor(pA, 1); pA += __shfl_xor(pA, 2);
      pB += __shfl_xor(pB, 1); pB += __shfl_xor(pB, 2);
      if (kq == 0) {
        p_l[rb*44 + j]        = pA;
        p_l[(rb+16)*44 + j]   = pB;
      }
    }
  }
  __syncthreads();
  partials_lds(p_l, t, sredm, sreds, redm,
               PmOut + (size_t)b*2560 + blk, PsOut + (size_t)b*2560 + blk);
}

extern "C" void kernel_launch(void* const* d_in, const int* in_sizes, int n_in,
                              void* d_out, int out_size, void* d_ws, size_t ws_size,
                              hipStream_t stream) {
  const float* nf  = (const float*)d_in[0];
  const float* fe  = (const float*)d_in[1];
  const float* W   = (const float*)d_in[2];
  const float* bin = (const float*)d_in[3];
  const float* U   = (const float*)d_in[4];
  const float* V   = (const float*)d_in[5];
  const float* q   = (const float*)d_in[6];
  const float* gw  = (const float*)d_in[7];
  const float* gb  = (const float*)d_in[8];
  float* out = (float*)d_out;
  float* wf  = (float*)d_ws;

  float* XU  = wf + XU_OFF;
  float* GX  = wf + GX_OFF;
  float* YP  = wf + YP_OFF;
  float* PMa = wf + PMA_OFF;
  float* PSa = wf + PSA_OFF;
  float* PMb = wf + PMB_OFF;
  float* PSb = wf + PSB_OFF;
  float* CWp = wf + CWS_OFF;
  float* MSb = wf + MS_OFF;
  double* PBn = (double*)(wf + PBN_OFF);
  double* PBf = (double*)(wf + PBF_OFF);
  double* ST  = (double*)(wf + ST_OFF);

  k_pre<<<2, 256, 0, stream>>>(W, bin, U, V, gw, CWp);
  k_cov<<<512, 256, 0, stream>>>(nf, CWp, PBn, NTOT/64);
  k_cov<<<20, 256, 0, stream>>>(fe, CWp, PBf, YROWS/64);
  k_comb<<<1, 256, 0, stream>>>(PBn, PBf, ST);
  k_yp2<<<YROWS/64, 256, 0, stream>>>(fe, CWp, q, ST, YP);
  k_I0b<<<NTOT/64, 256, 0, stream>>>(nf, CWp, ST, YP, XU, GX, PMa, PSa);
  k_comb2<<<32, 256, 0, stream>>>(PMa, PSa, MSb);
  k_fused5<0><<<NTOT/64, 256, 0, stream>>>(XU, GX, YP, CWp, gb, MSb, PMb, PSb, nullptr);
  k_comb2<<<32, 256, 0, stream>>>(PMb, PSb, MSb);
  k_fused5<1><<<NTOT/64, 256, 0, stream>>>(XU, GX, YP, CWp, gb, MSb, nullptr, nullptr, out);
}

// Round 9
// 254.699 us; speedup vs baseline: 1.3242x; 1.3242x over previous
//
#include <hip/hip_runtime.h>
#include <math.h>

namespace {
constexpr int BB = 32, NPG = 4096, NTOT = BB*NPG, C = 128, FIN = 64, KK = 32, JJ = 40;
constexpr int YROWS = BB*JJ; // 1280
constexpr float EPS = 1e-5f;

// CW (precomputed folded constants) float offsets
constexpr int CW_WU  = 0;      // [64][32] Wu[d][k] = sum_c W[c][d]*U[c][k]
constexpr int CW_WV  = 2048;   // [64][32] Wv[d][k] = sum_c W[c][d]*V[c][k]
constexpr int CW_VU  = 4096;   // [32][32] VU[k'][k] = sum_c V[c][k']*U[c][k]
constexpr int CW_WG  = 5120;   // [64]     sum_c W[c][d]*gw[c]
constexpr int CW_VGX = 5184;   // [32]     sum_c V[c][k]*gw[c]
constexpr int CW_VGH = 5216;   // [32]     sum_c V[c][k]*gw[128+c]
constexpr int CW_CBU = 5248;   // [32]     sum_c b[c]*U[c][k]
constexpr int CW_CSU = 5280;   // [32]     sum_c U[c][k]
constexpr int CW_CBV = 5312;   // [32]     sum_c b[c]*V[c][k]
constexpr int CW_CSV = 5344;   // [32]     sum_c V[c][k]
constexpr int CW_SC  = 5376;   // bG = b.gw[0:128], sG = sum gw[0:128]
constexpr int CW_G   = 5384;   // [64][64] G[d][e] = sum_c W[c][d]*W[c][e]
constexpr int CW_WB  = 9480;   // [64]     wb[d] = sum_c W[c][d]*b[c]
constexpr int CW_SW  = 9544;   // [64]     sw[d] = sum_c W[c][d]
constexpr int CW_SB  = 9608;   // sb = sum b, sb2 = sum b^2
constexpr int CW_SIZE = 9610;

// workspace layout (float offsets), all fp32 except ST/PB (double)
constexpr size_t XU_OFF  = 0;                               // NTOT*32
constexpr size_t GX_OFF  = XU_OFF + (size_t)NTOT*KK;        // NTOT
constexpr size_t YP_OFF  = GX_OFF + (size_t)NTOT;           // 1280*32
constexpr size_t PMA_OFF = YP_OFF + (size_t)YROWS*KK;       // 32*40*64
constexpr size_t PSA_OFF = PMA_OFF + 81920;
constexpr size_t PMB_OFF = PSA_OFF + 81920;
constexpr size_t PSB_OFF = PMB_OFF + 81920;
constexpr size_t CWS_OFF = PSB_OFF + 81920;
constexpr size_t PBN_OFF = CWS_OFF + 9612;                  // 512 double-pairs (nf)
constexpr size_t PBF_OFF = PBN_OFF + 2048;                  // 20 double-pairs (fe)
constexpr size_t MS_OFF  = PBF_OFF + 80;                    // 32*80 (M,Si per graph)
constexpr size_t ST_OFF  = MS_OFF + 2560;                   // 4 doubles
constexpr size_t IBF_OFF = ST_OFF + 8;                      // NTOT*40 (I matrix)
}

#define ACC8(A, wv, u0, u1) do { \
  A[0] += (wv)*(u0).x; A[1] += (wv)*(u0).y; A[2] += (wv)*(u0).z; A[3] += (wv)*(u0).w; \
  A[4] += (wv)*(u1).x; A[5] += (wv)*(u1).y; A[6] += (wv)*(u1).z; A[7] += (wv)*(u1).w; } while(0)

__device__ __forceinline__ float dot4(const float4 a, const float4 b) {
  return a.x*b.x + a.y*b.y + a.z*b.z + a.w*b.w;
}
__device__ __forceinline__ float dot8v(const float x[8], const float4 y0, const float4 y1) {
  return x[0]*y0.x + x[1]*y0.y + x[2]*y0.z + x[3]*y0.w
       + x[4]*y1.x + x[5]*y1.y + x[6]*y1.z + x[7]*y1.w;
}
__device__ __forceinline__ float sigm(const float x) { return 1.f/(1.f + __expf(-x)); }

// ---------------------------------------------------------------------------
// K0: fold W/U/V/gate into small matrices (unchanged, proven).
// ---------------------------------------------------------------------------
__global__ __launch_bounds__(256)
void k_pre(const float* __restrict__ W, const float* __restrict__ b,
           const float* __restrict__ U, const float* __restrict__ V,
           const float* __restrict__ gw, float* __restrict__ CWo) {
  __shared__ float W_l[128*64];
  __shared__ float V_l[128*32];
  const int t = threadIdx.x;
  for (int f = t; f < 2048; f += 256) *(float4*)(W_l + 4*f) = *(const float4*)(W + 4*f);
  if (blockIdx.x == 0)
    for (int f = t; f < 1024; f += 256) *(float4*)(V_l + 4*f) = *(const float4*)(V + 4*f);
  __syncthreads();
  if (blockIdx.x == 1) {
    const int d = t >> 2, e0 = (t & 3) * 16;
    float g[16];
    #pragma unroll
    for (int i = 0; i < 16; ++i) g[i] = 0.f;
    for (int c = 0; c < 128; ++c) {
      const float wv = W_l[c*64 + d];
      #pragma unroll
      for (int u = 0; u < 4; ++u) {
        const float4 we = *(const float4*)(W_l + c*64 + e0 + 4*u);
        g[4*u+0] += wv*we.x; g[4*u+1] += wv*we.y;
        g[4*u+2] += wv*we.z; g[4*u+3] += wv*we.w;
      }
    }
    #pragma unroll
    for (int u = 0; u < 4; ++u)
      *(float4*)(CWo + CW_G + d*64 + e0 + 4*u) = make_float4(g[4*u],g[4*u+1],g[4*u+2],g[4*u+3]);
    if (t < 64) {
      float awb = 0.f, asw = 0.f;
      for (int c = 0; c < 128; ++c) {
        const float wv = W_l[c*64 + t];
        awb += wv * b[c]; asw += wv;
      }
      CWo[CW_WB + t] = awb; CWo[CW_SW + t] = asw;
    }
    if (t == 0) {
      float sb = 0.f, sb2 = 0.f;
      for (int c = 0; c < 128; ++c) { sb += b[c]; sb2 += b[c]*b[c]; }
      CWo[CW_SB+0] = sb; CWo[CW_SB+1] = sb2;
    }
    return;
  }
  {
    const int d = t >> 2, k0 = (t & 3) * 8;
    float au[8] = {0,0,0,0,0,0,0,0};
    float av[8] = {0,0,0,0,0,0,0,0};
    for (int c = 0; c < 128; ++c) {
      const float wv = W_l[c*64 + d];
      const float4 u0 = *(const float4*)(U + c*32 + k0);
      const float4 u1 = *(const float4*)(U + c*32 + k0 + 4);
      ACC8(au, wv, u0, u1);
      const float4 v0 = *(const float4*)(V_l + c*32 + k0);
      const float4 v1 = *(const float4*)(V_l + c*32 + k0 + 4);
      ACC8(av, wv, v0, v1);
    }
    *(float4*)(CWo + CW_WU + d*32 + k0)     = make_float4(au[0],au[1],au[2],au[3]);
    *(float4*)(CWo + CW_WU + d*32 + k0 + 4) = make_float4(au[4],au[5],au[6],au[7]);
    *(float4*)(CWo + CW_WV + d*32 + k0)     = make_float4(av[0],av[1],av[2],av[3]);
    *(float4*)(CWo + CW_WV + d*32 + k0 + 4) = make_float4(av[4],av[5],av[6],av[7]);
  }
  if (t < 128) {
    const int kp = t >> 2, k0 = (t & 3) * 8;
    float a[8] = {0,0,0,0,0,0,0,0};
    for (int c = 0; c < 128; ++c) {
      const float vv = V_l[c*32 + kp];
      const float4 u0 = *(const float4*)(U + c*32 + k0);
      const float4 u1 = *(const float4*)(U + c*32 + k0 + 4);
      ACC8(a, vv, u0, u1);
    }
    *(float4*)(CWo + CW_VU + kp*32 + k0)     = make_float4(a[0],a[1],a[2],a[3]);
    *(float4*)(CWo + CW_VU + kp*32 + k0 + 4) = make_float4(a[4],a[5],a[6],a[7]);
  }
  if (t < 64) {
    float a = 0.f;
    for (int c = 0; c < 128; ++c) a += W_l[c*64 + t] * gw[c];
    CWo[CW_WG + t] = a;
  }
  if (t < 32) {
    float a1=0,a2=0,a3=0,a4=0,a5=0,a6=0;
    for (int c = 0; c < 128; ++c) {
      const float uv = U[c*32 + t], vv = V_l[c*32 + t], bc = b[c];
      a1 += vv*gw[c]; a2 += vv*gw[128+c];
      a3 += bc*uv;    a4 += uv;
      a5 += bc*vv;    a6 += vv;
    }
    CWo[CW_VGX+t]=a1; CWo[CW_VGH+t]=a2; CWo[CW_CBU+t]=a3; CWo[CW_CSU+t]=a4;
    CWo[CW_CBV+t]=a5; CWo[CW_CSV+t]=a6;
  }
  if (t == 0) {
    float bg=0.f, sg=0.f;
    for (int c = 0; c < 128; ++c) { bg += b[c]*gw[c]; sg += gw[c]; }
    CWo[CW_SC+0]=bg; CWo[CW_SC+1]=sg;
  }
}

// ---------------------------------------------------------------------------
// K1: stats via second moments (unchanged, proven). Per-block pair to PB.
// ---------------------------------------------------------------------------
__global__ __launch_bounds__(256,6)
void k_cov(const float* __restrict__ inp, const float* __restrict__ CW,
           double* __restrict__ PB, const int ntiles) {
  __shared__ float a_l[64*64];
  __shared__ float red[12];
  const int t = threadIdx.x;
  const int dg = t >> 4, eg = t & 15;
  const int d0 = dg*4, e0 = eg*4;
  float av1 = 0.f, av2 = 0.f, avb = 0.f;
  int nt = 0;
  for (int tile = blockIdx.x; tile < ntiles; tile += gridDim.x) {
    __syncthreads();
    const size_t r0 = (size_t)tile * 64;
    #pragma unroll
    for (int s = 0; s < 4; ++s) {
      int f = (t + 256*s) * 4;
      *(float4*)(a_l + f) = *(const float4*)(inp + r0*FIN + f);
    }
    __syncthreads();
    float S[4][4];
    #pragma unroll
    for (int i=0;i<4;i++)
      #pragma unroll
      for (int j=0;j<4;j++) S[i][j] = 0.f;
    float4 cs = make_float4(0.f,0.f,0.f,0.f);
    #pragma unroll 4
    for (int r = 0; r < 64; ++r) {
      const float4 ad = *(const float4*)(a_l + r*64 + d0);
      const float4 ae = *(const float4*)(a_l + r*64 + e0);
      S[0][0]+=ad.x*ae.x; S[0][1]+=ad.x*ae.y; S[0][2]+=ad.x*ae.z; S[0][3]+=ad.x*ae.w;
      S[1][0]+=ad.y*ae.x; S[1][1]+=ad.y*ae.y; S[1][2]+=ad.y*ae.z; S[1][3]+=ad.y*ae.w;
      S[2][0]+=ad.z*ae.x; S[2][1]+=ad.z*ae.y; S[2][2]+=ad.z*ae.z; S[2][3]+=ad.z*ae.w;
      S[3][0]+=ad.w*ae.x; S[3][1]+=ad.w*ae.y; S[3][2]+=ad.w*ae.z; S[3][3]+=ad.w*ae.w;
      cs.x += ad.x; cs.y += ad.y; cs.z += ad.z; cs.w += ad.w;
    }
    #pragma unroll
    for (int i = 0; i < 4; ++i) {
      const float4 g4 = *(const float4*)(CW + CW_G + (d0+i)*64 + e0);
      av2 += S[i][0]*g4.x + S[i][1]*g4.y + S[i][2]*g4.z + S[i][3]*g4.w;
    }
    if (eg == 0) {
      const float4 sw4 = *(const float4*)(CW + CW_SW + d0);
      const float4 wb4 = *(const float4*)(CW + CW_WB + d0);
      av1 += cs.x*sw4.x + cs.y*sw4.y + cs.z*sw4.z + cs.w*sw4.w;
      avb += cs.x*wb4.x + cs.y*wb4.y + cs.z*wb4.z + cs.w*wb4.w;
    }
    ++nt;
  }
  #pragma unroll
  for (int off = 32; off > 0; off >>= 1) {
    av2 += __shfl_xor(av2, off);
    av1 += __shfl_xor(av1, off);
    avb += __shfl_xor(avb, off);
  }
  const int w = t >> 6;
  if ((t & 63) == 0) { red[w*3] = av1; red[w*3+1] = av2; red[w*3+2] = avb; }
  __syncthreads();
  if (t == 0) {
    const float sb = CW[CW_SB], sb2 = CW[CW_SB+1];
    const double rowsB = 64.0 * (double)nt;
    const double s1 = (double)(red[0]+red[3]+red[6]+red[9]);
    const double s2 = (double)(red[1]+red[4]+red[7]+red[10]);
    const double sB = (double)(red[2]+red[5]+red[8]+red[11]);
    PB[(size_t)blockIdx.x*2 + 0] = s1 + rowsB*(double)sb;
    PB[(size_t)blockIdx.x*2 + 1] = s2 + 2.0*sB + rowsB*(double)sb2;
  }
}

// ---------------------------------------------------------------------------
// K1b: combine per-block double-pairs into ST[0..3]. One block.
// ---------------------------------------------------------------------------
__global__ __launch_bounds__(256)
void k_comb(const double* __restrict__ PBn, const double* __restrict__ PBf,
            double* __restrict__ ST) {
  __shared__ double red[8];
  const int t = threadIdx.x;
  double a = PBn[2*t] + PBn[2*(t+256)];
  double b = PBn[2*t+1] + PBn[2*(t+256)+1];
  #pragma unroll
  for (int off = 32; off > 0; off >>= 1) {
    a += __shfl_down(a, off);
    b += __shfl_down(b, off);
  }
  if ((t & 63) == 0) { red[(t>>6)*2] = a; red[(t>>6)*2+1] = b; }
  __syncthreads();
  if (t == 0) {
    ST[0] = red[0]+red[2]+red[4]+red[6];
    ST[1] = red[1]+red[3]+red[5]+red[7];
  }
  if (t < 64) {
    double c = (t < 20) ? PBf[2*t]   : 0.0;
    double d = (t < 20) ? PBf[2*t+1] : 0.0;
    #pragma unroll
    for (int off = 32; off > 0; off >>= 1) {
      c += __shfl_down(c, off);
      d += __shfl_down(d, off);
    }
    if (t == 0) { ST[2] = c; ST[3] = d; }
  }
}

// ---------------------------------------------------------------------------
// K1c: combine softmax partials (Pm/Ps 64-wide) into per-(b,j) M, 1/S.
// grid = 32 (one block per graph).  (proven r7/r8)
// ---------------------------------------------------------------------------
__global__ __launch_bounds__(256)
void k_comb2(const float* __restrict__ Pm, const float* __restrict__ Ps,
             float* __restrict__ MS) {
  __shared__ float Mq[160], Sq[160], Msh[40];
  const int t = threadIdx.x;
  const int b = blockIdx.x;
  const int j = t >> 2, q = t & 3;
  float pm[16];
  if (t < 160) {
    float m = 0.f;
    #pragma unroll
    for (int u = 0; u < 16; ++u) {
      pm[u] = Pm[(size_t)b*2560 + j*64 + q*16 + u];
      m = fmaxf(m, pm[u]);
    }
    Mq[t] = m;
  }
  __syncthreads();
  if (t < 40) Msh[t] = fmaxf(fmaxf(Mq[4*t], Mq[4*t+1]), fmaxf(Mq[4*t+2], Mq[4*t+3]));
  __syncthreads();
  if (t < 160) {
    const float M = Msh[j];
    float s = 0.f;
    #pragma unroll
    for (int u = 0; u < 16; ++u)
      s += Ps[(size_t)b*2560 + j*64 + q*16 + u] * __expf(pm[u] - M);
    Sq[t] = s;
  }
  __syncthreads();
  if (t < 40) {
    const float S = Sq[4*t] + Sq[4*t+1] + Sq[4*t+2] + Sq[4*t+3];
    MS[(size_t)b*80 + t] = Msh[t];
    MS[(size_t)b*80 + 40 + t] = 1.f/S;
  }
}

// ---------------------------------------------------------------------------
// irow_compute (round-4 proven): per-lane 8 ks, 4-lane groups, xor1/2 = DPP.
// ypj layout [j][k], stride 32.
// ---------------------------------------------------------------------------
__device__ __forceinline__ void irow_compute(const float* ypj, const float xp[8],
                                             const int kq, float4 p[10]) {
  #pragma unroll
  for (int m = 0; m < 10; ++m) {
    float4 acc;
    #pragma unroll
    for (int jj = 0; jj < 4; ++jj) {
      const int j = 4*m + jj;
      const float4 y0 = *(const float4*)(ypj + j*32 + kq*8);
      const float4 y1 = *(const float4*)(ypj + j*32 + kq*8 + 4);
      const float s = xp[0]*y0.x + xp[1]*y0.y + xp[2]*y0.z + xp[3]*y0.w
                    + xp[4]*y1.x + xp[5]*y1.y + xp[6]*y1.z + xp[7]*y1.w;
      if (jj==0) acc.x = s; else if (jj==1) acc.y = s; else if (jj==2) acc.z = s; else acc.w = s;
    }
    acc.x += __shfl_xor(acc.x,1); acc.x += __shfl_xor(acc.x,2);
    acc.y += __shfl_xor(acc.y,1); acc.y += __shfl_xor(acc.y,2);
    acc.z += __shfl_xor(acc.z,1); acc.z += __shfl_xor(acc.z,2);
    acc.w += __shfl_xor(acc.w,1); acc.w += __shfl_xor(acc.w,2);
    p[m] = acc;
  }
}

// ---------------------------------------------------------------------------
// partials_out (round-4 proven): softmax partials from register p[10].
// ---------------------------------------------------------------------------
__device__ __forceinline__ void partials_out(const float4 p[10], const int t, const int kq,
    float* sredm, float* sreds, float* redm,
    float* __restrict__ PmB, float* __restrict__ PsB) {
  float ev[10];
  #pragma unroll
  for (int m = 0; m < 10; ++m) {
    const float4 qv = p[m];
    ev[m] = (kq&1) ? ((kq&2)? qv.w : qv.y) : ((kq&2)? qv.z : qv.x);
  }
  const int w = t >> 6, tl = t & 63;
  float mv[10];
  #pragma unroll
  for (int m = 0; m < 10; ++m) {
    mv[m] = ev[m];
    mv[m] = fmaxf(mv[m], __shfl_xor(mv[m], 4));
    mv[m] = fmaxf(mv[m], __shfl_xor(mv[m], 8));
    mv[m] = fmaxf(mv[m], __shfl_xor(mv[m], 16));
    mv[m] = fmaxf(mv[m], __shfl_xor(mv[m], 32));
  }
  if (tl < 4) {
    #pragma unroll
    for (int m = 0; m < 10; ++m) sredm[w*40 + 4*m + kq] = mv[m];
  }
  __syncthreads();
  if (t < 40)
    redm[t] = fmaxf(fmaxf(sredm[t], sredm[40+t]), fmaxf(sredm[80+t], sredm[120+t]));
  __syncthreads();
  float es[10];
  #pragma unroll
  for (int m = 0; m < 10; ++m) {
    const float M = redm[4*m + kq];
    es[m] = __expf(ev[m]-M);
    es[m] += __shfl_xor(es[m], 4);
    es[m] += __shfl_xor(es[m], 8);
    es[m] += __shfl_xor(es[m], 16);
    es[m] += __shfl_xor(es[m], 32);
  }
  if (tl < 4) {
    #pragma unroll
    for (int m = 0; m < 10; ++m) sreds[w*40 + 4*m + kq] = es[m];
  }
  __syncthreads();
  if (t < 40) {
    PmB[(size_t)t*64] = redm[t];
    PsB[(size_t)t*64] = sreds[t]+sreds[40+t]+sreds[80+t]+sreds[120+t];
  }
}

// ---------------------------------------------------------------------------
// partials_lds: softmax partials from p staged in LDS (stride 44). Proven.
// ---------------------------------------------------------------------------
__device__ __forceinline__ void partials_lds(const float* p_l, const int t,
    float* sredm, float* sreds, float* redm,
    float* __restrict__ PmB, float* __restrict__ PsB) {
  const int r2 = t >> 2, kq = t & 3;
  const int w = t >> 6, tl = t & 63;
  float ev[10];
  #pragma unroll
  for (int m = 0; m < 10; ++m) ev[m] = p_l[r2*44 + 4*m + kq];
  float mv[10];
  #pragma unroll
  for (int m = 0; m < 10; ++m) {
    mv[m] = ev[m];
    mv[m] = fmaxf(mv[m], __shfl_xor(mv[m], 4));
    mv[m] = fmaxf(mv[m], __shfl_xor(mv[m], 8));
    mv[m] = fmaxf(mv[m], __shfl_xor(mv[m], 16));
    mv[m] = fmaxf(mv[m], __shfl_xor(mv[m], 32));
  }
  if (tl < 4) {
    #pragma unroll
    for (int m = 0; m < 10; ++m) sredm[w*40 + 4*m + kq] = mv[m];
  }
  __syncthreads();
  if (t < 40)
    redm[t] = fmaxf(fmaxf(sredm[t], sredm[40+t]), fmaxf(sredm[80+t], sredm[120+t]));
  __syncthreads();
  float es[10];
  #pragma unroll
  for (int m = 0; m < 10; ++m) {
    const float M = redm[4*m + kq];
    es[m] = __expf(ev[m]-M);
    es[m] += __shfl_xor(es[m], 4);
    es[m] += __shfl_xor(es[m], 8);
    es[m] += __shfl_xor(es[m], 16);
    es[m] += __shfl_xor(es[m], 32);
  }
  if (tl < 4) {
    #pragma unroll
    for (int m = 0; m < 10; ++m) sreds[w*40 + 4*m + kq] = es[m];
  }
  __syncthreads();
  if (t < 40) {
    PmB[(size_t)t*64] = redm[t];
    PsB[(size_t)t*64] = sreds[t]+sreds[40+t]+sreds[80+t]+sreds[120+t];
  }
}

// ---------------------------------------------------------------------------
// K2: y_p directly from fe (unchanged, proven).
// ---------------------------------------------------------------------------
__global__ __launch_bounds__(256,4)
void k_yp2(const float* __restrict__ fe, const float* __restrict__ CW,
           const float* __restrict__ q, const double* __restrict__ ST,
           float* __restrict__ yp) {
  __shared__ float in_t[64*64];
  __shared__ float Wl[64*32];
  const int t = threadIdx.x;
  const int r0 = blockIdx.x * 64;
  #pragma unroll
  for (int s = 0; s < 4; ++s) {
    int f = (t + 256*s) * 4;
    int r = f >> 6, d = f & 63;
    float4 v = *(const float4*)(fe + (size_t)r0*FIN + f);
    *(float4*)(in_t + r*64 + (d ^ ((r & 7) * 8))) = v;
  }
  #pragma unroll
  for (int s = 0; s < 2; ++s) {
    int f = (t + 256*s) * 4;
    *(float4*)(Wl + f) = *(const float4*)(CW + CW_WV + f);
  }
  __syncthreads();
  const double cy = (double)YROWS * (double)C;
  const double myd = ST[2]/cy, vy = ST[3]/cy - myd*myd;
  const float ry = (float)(1.0/sqrt(vy + (double)EPS));
  const float mr = (float)myd * ry;
  const int r2 = t >> 2, kq = t & 3;
  const int swz = (r2 & 7) * 8;
  float acc[8] = {0,0,0,0,0,0,0,0};
  #pragma unroll
  for (int dc = 0; dc < 16; ++dc) {
    const int d = dc*4;
    const float4 a = *(const float4*)(in_t + r2*64 + (d ^ swz));
    { const float4 w0 = *(const float4*)(Wl + (d+0)*32 + kq*8);
      const float4 w1 = *(const float4*)(Wl + (d+0)*32 + kq*8 + 4); ACC8(acc, a.x, w0, w1); }
    { const float4 w0 = *(const float4*)(Wl + (d+1)*32 + kq*8);
      const float4 w1 = *(const float4*)(Wl + (d+1)*32 + kq*8 + 4); ACC8(acc, a.y, w0, w1); }
    { const float4 w0 = *(const float4*)(Wl + (d+2)*32 + kq*8);
      const float4 w1 = *(const float4*)(Wl + (d+2)*32 + kq*8 + 4); ACC8(acc, a.z, w0, w1); }
    { const float4 w0 = *(const float4*)(Wl + (d+3)*32 + kq*8);
      const float4 w1 = *(const float4*)(Wl + (d+3)*32 + kq*8 + 4); ACC8(acc, a.w, w0, w1); }
  }
  #pragma unroll
  for (int i = 0; i < 8; ++i) {
    const int k = kq*8 + i;
    const float typ = ry*(acc[i] + CW[CW_CBV+k]) - mr*CW[CW_CSV+k];
    float v = fmaxf(typ, 0.f);
    acc[i] = fmaxf(q[k]*v, 0.f);
  }
  *(float4*)(yp + (size_t)(r0+r2)*KK + kq*8)     = make_float4(acc[0],acc[1],acc[2],acc[3]);
  *(float4*)(yp + (size_t)(r0+r2)*KK + kq*8 + 4) = make_float4(acc[4],acc[5],acc[6],acc[7]);
}

// ---------------------------------------------------------------------------
// K3: layer-0, 4-row register-blocked; streamed I-row -> p_l -> partials,
// then coalesced I write to Ibf (new: next kernel reads it instead of irow1).
// ---------------------------------------------------------------------------
__global__ __launch_bounds__(256,4)
void k_I0b(const float* __restrict__ nf, const float* __restrict__ CW,
           const double* __restrict__ ST, const float* __restrict__ yp,
           float* __restrict__ XU, float* __restrict__ GX,
           float* __restrict__ Pm, float* __restrict__ Ps,
           float* __restrict__ Ibf) {
  __shared__ __align__(16) float in_t[64*68];   // overlaid by p_l (64*44) later
  __shared__ __align__(16) float Wl[64*36];     // row d -> (d&15)*4 + (d>>4)
  __shared__ __align__(16) float ypj[40*40];
  __shared__ __align__(16) float wgl[64];
  __shared__ float sredm[160], sreds[160], redm[40];
  float* p_l = in_t;
  const int t = threadIdx.x;
  const int bid = blockIdx.x;
  const int b = bid >> 6, blk = bid & 63;
  const size_t rowbase = (size_t)b*NPG + (size_t)blk*64;
  #pragma unroll
  for (int s = 0; s < 4; ++s) {
    int f = (t + 256*s) * 4;
    int r = f >> 6, d = f & 63;
    *(float4*)(in_t + r*68 + d) = *(const float4*)(nf + rowbase*FIN + f);
  }
  #pragma unroll
  for (int s = 0; s < 2; ++s) {
    int idx = t + 256*s;
    int d = idx >> 3, kc = idx & 7;
    *(float4*)(Wl + ((d&15)*4 + (d>>4))*36 + kc*4) = *(const float4*)(CW + CW_WU + idx*4);
  }
  for (int f4v = t; f4v < 320; f4v += 256) {
    int j = f4v >> 3, kc = f4v & 7;
    *(float4*)(ypj + j*40 + kc*4) = *(const float4*)(yp + (size_t)b*(JJ*KK) + f4v*4);
  }
  if (t < 64) wgl[t] = CW[CW_WG + t];
  __syncthreads();
  const double cx = (double)NTOT * (double)C;
  const double mx = ST[0]/cx, vx = ST[1]/cx - mx*mx;
  const float rx = (float)(1.0/sqrt(vx + (double)EPS));
  const float mr = (float)mx * rx;
  const int kq = t & 3, X = (t >> 2) & 3, rr = t >> 4;
  float acc[4][8];
  #pragma unroll
  for (int i=0;i<4;i++)
    #pragma unroll
    for (int u=0;u<8;u++) acc[i][u] = 0.f;
  #pragma unroll
  for (int dd = 0; dd < 4; ++dd) {
    float4 a4[4];
    #pragma unroll
    for (int i = 0; i < 4; ++i)
      a4[i] = *(const float4*)(in_t + (rr+16*i)*68 + X*16 + dd*4);
    #pragma unroll
    for (int qd = 0; qd < 4; ++qd) {
      const int lrow = (dd*4 + qd)*4 + X;
      const float4 w0 = *(const float4*)(Wl + lrow*36 + kq*8);
      const float4 w1 = *(const float4*)(Wl + lrow*36 + kq*8 + 4);
      #pragma unroll
      for (int i = 0; i < 4; ++i) {
        const float av = (qd==0)? a4[i].x : (qd==1)? a4[i].y : (qd==2)? a4[i].z : a4[i].w;
        ACC8(acc[i], av, w0, w1);
      }
    }
  }
  #pragma unroll
  for (int i = 0; i < 4; ++i)
    #pragma unroll
    for (int u = 0; u < 8; ++u) {
      acc[i][u] += __shfl_xor(acc[i][u], 4);
      acc[i][u] += __shfl_xor(acc[i][u], 8);
    }
  float gp[4];
  #pragma unroll
  for (int i = 0; i < 4; ++i) {
    const float4 a = *(const float4*)(in_t + (rr+16*i)*68 + X*16 + kq*4);
    const float4 w = *(const float4*)(wgl + X*16 + kq*4);
    gp[i] = dot4(a, w);
    gp[i] += __shfl_xor(gp[i], 1);
    gp[i] += __shfl_xor(gp[i], 2);
    gp[i] += __shfl_xor(gp[i], 4);
    gp[i] += __shfl_xor(gp[i], 8);
  }
  const float4 cb0 = *(const float4*)(CW + CW_CBU + kq*8);
  const float4 cb1 = *(const float4*)(CW + CW_CBU + kq*8 + 4);
  const float4 cu0 = *(const float4*)(CW + CW_CSU + kq*8);
  const float4 cu1 = *(const float4*)(CW + CW_CSU + kq*8 + 4);
  float xp[4][8];
  #pragma unroll
  for (int i = 0; i < 4; ++i) {
    acc[i][0] = rx*(acc[i][0] + cb0.x) - mr*cu0.x;
    acc[i][1] = rx*(acc[i][1] + cb0.y) - mr*cu0.y;
    acc[i][2] = rx*(acc[i][2] + cb0.z) - mr*cu0.z;
    acc[i][3] = rx*(acc[i][3] + cb0.w) - mr*cu0.w;
    acc[i][4] = rx*(acc[i][4] + cb1.x) - mr*cu1.x;
    acc[i][5] = rx*(acc[i][5] + cb1.y) - mr*cu1.y;
    acc[i][6] = rx*(acc[i][6] + cb1.z) - mr*cu1.z;
    acc[i][7] = rx*(acc[i][7] + cb1.w) - mr*cu1.w;
    #pragma unroll
    for (int u = 0; u < 8; ++u) xp[i][u] = fmaxf(acc[i][u], 0.f);
  }
  if (X == 0) {
    const float bG = CW[CW_SC], sG = CW[CW_SC+1];
    #pragma unroll
    for (int i = 0; i < 4; ++i) {
      const size_t row = rowbase + rr + 16*i;
      *(float4*)(XU + row*KK + kq*8)     = make_float4(acc[i][0],acc[i][1],acc[i][2],acc[i][3]);
      *(float4*)(XU + row*KK + kq*8 + 4) = make_float4(acc[i][4],acc[i][5],acc[i][6],acc[i][7]);
      if (kq == 0) GX[row] = rx*(gp[i] + bG) - mr*sG;
    }
  }
  __syncthreads();                       // all in_t reads done; overlay p_l
  #pragma unroll 2
  for (int jj = 0; jj < 10; ++jj) {
    const int j = X*10 + jj;
    const float4 y0 = *(const float4*)(ypj + j*40 + kq*8);
    const float4 y1 = *(const float4*)(ypj + j*40 + kq*8 + 4);
    float p4[4];
    #pragma unroll
    for (int i = 0; i < 4; ++i) p4[i] = dot8v(xp[i], y0, y1);
    #pragma unroll
    for (int i = 0; i < 4; ++i) {
      p4[i] += __shfl_xor(p4[i], 1);
      p4[i] += __shfl_xor(p4[i], 2);
    }
    if (kq == 0) {
      #pragma unroll
      for (int i = 0; i < 4; ++i)
        p_l[(rr+16*i)*44 + j] = p4[i];
    }
  }
  __syncthreads();
  partials_lds(p_l, t, sredm, sreds, redm,
               Pm + (size_t)b*2560 + blk, Ps + (size_t)b*2560 + blk);
  // I write (p_l untouched by partials_lds; coalesced f4)
  for (int f4v = t; f4v < 640; f4v += 256) {
    const int row = f4v / 10, jq = f4v - row*10;
    *(float4*)(Ibf + (rowbase+row)*JJ + jq*4) = *(const float4*)(p_l + row*44 + jq*4);
  }
}

// ---------------------------------------------------------------------------
// K4: fused layer update (round-4 proven body, irow1 replaced by Ibf read):
// e_l = exp(I-M)*Si from Ibf -> h = A@yp -> hu = h@VU + gate + blend ->
// one irow -> (FINAL: out) else (partials + I write to Ibf).
// ---------------------------------------------------------------------------
template<int FINAL>
__global__ __launch_bounds__(256,4)
void k_fused6(float* __restrict__ XU, float* __restrict__ GX,
              float* __restrict__ Ibf,
              const float* __restrict__ yp, const float* __restrict__ CW,
              const float* __restrict__ gb, const float* __restrict__ MS,
              float* __restrict__ PmOut, float* __restrict__ PsOut,
              float* __restrict__ outp) {
  __shared__ float ypj[40*32];
  __shared__ float e_l[64*44];           // A-tile; sred overlay after phase B
  __shared__ float h_l[64*40];
  __shared__ float VUl[32*32];
  __shared__ float M_l[40], Si_l[40];
  __shared__ float vgxl[32], vghl[32];
  float* sredm = e_l;
  float* sreds = e_l + 160;
  float* redm  = e_l + 320;
  const int t = threadIdx.x;
  const int bid = blockIdx.x;
  const int b = bid >> 6, blk = bid & 63;
  const size_t rowbase = (size_t)b*NPG + (size_t)blk*64;
  for (int f4v = t; f4v < 320; f4v += 256)
    *(float4*)(ypj + f4v*4) = *(const float4*)(yp + (size_t)b*(JJ*KK) + f4v*4);
  { const int f = t*4;
    *(float4*)(VUl + f) = *(const float4*)(CW + CW_VU + f); }
  if (t < 32) { vgxl[t] = CW[CW_VGX+t]; vghl[t] = CW[CW_VGH+t]; }
  if (t < 40) { M_l[t] = MS[(size_t)b*80 + t]; Si_l[t] = MS[(size_t)b*80 + 40 + t]; }
  __syncthreads();
  // e_l from Ibf (replaces irow1): e = exp(I - M) * Si
  for (int f4v = t; f4v < 640; f4v += 256) {
    const int row = f4v / 10, jq = f4v - row*10;
    const float4 iv = *(const float4*)(Ibf + (rowbase+row)*JJ + jq*4);
    float4 e4;
    e4.x = __expf(iv.x - M_l[jq*4+0]) * Si_l[jq*4+0];
    e4.y = __expf(iv.y - M_l[jq*4+1]) * Si_l[jq*4+1];
    e4.z = __expf(iv.z - M_l[jq*4+2]) * Si_l[jq*4+2];
    e4.w = __expf(iv.w - M_l[jq*4+3]) * Si_l[jq*4+3];
    *(float4*)(e_l + row*44 + jq*4) = e4;
  }
  const int r2 = t >> 2, kq = t & 3;
  float xu[8];
  {
    const float4 x0 = *(const float4*)(XU + (rowbase+r2)*KK + kq*8);
    const float4 x1 = *(const float4*)(XU + (rowbase+r2)*KK + kq*8 + 4);
    xu[0]=x0.x; xu[1]=x0.y; xu[2]=x0.z; xu[3]=x0.w;
    xu[4]=x1.x; xu[5]=x1.y; xu[6]=x1.z; xu[7]=x1.w;
  }
  const float gx = GX[rowbase + r2];
  __syncthreads();
  // phase B: h[n][k] = relu(sum_j A[n][j]*yp[j][k])  (rows {rq, rq+32})
  {
    const int rq = t >> 3, kc = t & 7;
    float4 h0 = make_float4(0.f,0.f,0.f,0.f), h1 = make_float4(0.f,0.f,0.f,0.f);
    #pragma unroll 4
    for (int j = 0; j < JJ; ++j) {
      const float4 yv = *(const float4*)(ypj + j*32 + kc*4);
      const float e0 = e_l[rq*44 + j];
      const float e1 = e_l[(rq+32)*44 + j];
      h0.x += e0*yv.x; h0.y += e0*yv.y; h0.z += e0*yv.z; h0.w += e0*yv.w;
      h1.x += e1*yv.x; h1.y += e1*yv.y; h1.z += e1*yv.z; h1.w += e1*yv.w;
    }
    h0.x = fmaxf(h0.x,0.f); h0.y = fmaxf(h0.y,0.f); h0.z = fmaxf(h0.z,0.f); h0.w = fmaxf(h0.w,0.f);
    h1.x = fmaxf(h1.x,0.f); h1.y = fmaxf(h1.y,0.f); h1.z = fmaxf(h1.z,0.f); h1.w = fmaxf(h1.w,0.f);
    *(float4*)(h_l + rq*40 + kc*4) = h0;
    *(float4*)(h_l + (rq+32)*40 + kc*4) = h1;
  }
  __syncthreads();
  // phase C: hu = h@VU, gate, blend in K-space
  float hu[8] = {0,0,0,0,0,0,0,0};
  float gh2 = 0.f, ghx = 0.f;
  #pragma unroll 8
  for (int kp = 0; kp < KK; ++kp) {
    const float hv = h_l[r2*40 + kp];
    gh2 += hv * vghl[kp];
    ghx += hv * vgxl[kp];
    const float4 v0 = *(const float4*)(VUl + kp*32 + kq*8);
    const float4 v1 = *(const float4*)(VUl + kp*32 + kq*8 + 4);
    ACC8(hu, hv, v0, v1);
  }
  const float z = 1.f/(1.f + __expf(-(gx + gh2 + gb[0])));
  float xp[8];
  #pragma unroll
  for (int i = 0; i < 8; ++i) {
    xu[i] = (1.f - z)*xu[i] + z*hu[i];
    xp[i] = fmaxf(xu[i], 0.f);
  }
  if (!FINAL) {
    *(float4*)(XU + (rowbase+r2)*KK + kq*8)     = make_float4(xu[0],xu[1],xu[2],xu[3]);
    *(float4*)(XU + (rowbase+r2)*KK + kq*8 + 4) = make_float4(xu[4],xu[5],xu[6],xu[7]);
    if (kq == 0) GX[rowbase + r2] = (1.f - z)*gx + z*ghx;
  }
  // single irow on updated xp
  float4 p[10];
  irow_compute(ypj, xp, kq, p);
  if (FINAL) {
    float s = 0.f;
    #pragma unroll
    for (int m = 0; m < 10; ++m)
      s += p[m].x*p[m].x + p[m].y*p[m].y + p[m].z*p[m].z + p[m].w*p[m].w;
    if (kq == 0) outp[rowbase + r2] = 1.f/(1.f + __expf(-s));
    return;
  }
  // I write: lane kq stores m with (m&3)==kq (full row covered across 4 lanes)
  #pragma unroll
  for (int m = 0; m < 10; ++m)
    if ((m & 3) == kq)
      *(float4*)(Ibf + (rowbase+r2)*JJ + 4*m) = p[m];
  partials_out(p, t, kq, sredm, sreds, redm,
               PmOut + (size_t)b*2560 + blk, PsOut + (size_t)b*2560 + blk);
}

extern "C" void kernel_launch(void* const* d_in, const int* in_sizes, int n_in,
                              void* d_out, int out_size, void* d_ws, size_t ws_size,
                              hipStream_t stream) {
  const float* nf  = (const float*)d_in[0];
  const float* fe  = (const float*)d_in[1];
  const float* W   = (const float*)d_in[2];
  const float* bin = (const float*)d_in[3];
  const float* U   = (const float*)d_in[4];
  const float* V   = (const float*)d_in[5];
  const float* q   = (const float*)d_in[6];
  const float* gw  = (const float*)d_in[7];
  const float* gb  = (const float*)d_in[8];
  float* out = (float*)d_out;
  float* wf  = (float*)d_ws;

  float* XU  = wf + XU_OFF;
  float* GX  = wf + GX_OFF;
  float* YP  = wf + YP_OFF;
  float* PMa = wf + PMA_OFF;
  float* PSa = wf + PSA_OFF;
  float* PMb = wf + PMB_OFF;
  float* PSb = wf + PSB_OFF;
  float* CWp = wf + CWS_OFF;
  float* MSb = wf + MS_OFF;
  float* IBF = wf + IBF_OFF;
  double* PBn = (double*)(wf + PBN_OFF);
  double* PBf = (double*)(wf + PBF_OFF);
  double* ST  = (double*)(wf + ST_OFF);

  k_pre<<<2, 256, 0, stream>>>(W, bin, U, V, gw, CWp);
  k_cov<<<512, 256, 0, stream>>>(nf, CWp, PBn, NTOT/64);
  k_cov<<<20, 256, 0, stream>>>(fe, CWp, PBf, YROWS/64);
  k_comb<<<1, 256, 0, stream>>>(PBn, PBf, ST);
  k_yp2<<<YROWS/64, 256, 0, stream>>>(fe, CWp, q, ST, YP);
  k_I0b<<<NTOT/64, 256, 0, stream>>>(nf, CWp, ST, YP, XU, GX, PMa, PSa, IBF);
  k_comb2<<<32, 256, 0, stream>>>(PMa, PSa, MSb);
  k_fused6<0><<<NTOT/64, 256, 0, stream>>>(XU, GX, IBF, YP, CWp, gb, MSb, PMb, PSb, nullptr);
  k_comb2<<<32, 256, 0, stream>>>(PMb, PSb, MSb);
  k_fused6<1><<<NTOT/64, 256, 0, stream>>>(XU, GX, IBF, YP, CWp, gb, MSb, nullptr, nullptr, out);
}

// Round 10
// 249.084 us; speedup vs baseline: 1.3540x; 1.0225x over previous
//
#include <hip/hip_runtime.h>
#include <math.h>

namespace {
constexpr int BB = 32, NPG = 4096, NTOT = BB*NPG, C = 128, FIN = 64, KK = 32, JJ = 40;
constexpr int YROWS = BB*JJ; // 1280
constexpr float EPS = 1e-5f;

// CW (precomputed folded constants) float offsets
constexpr int CW_WU  = 0;      // [64][32] Wu[d][k] = sum_c W[c][d]*U[c][k]
constexpr int CW_WV  = 2048;   // [64][32] Wv[d][k] = sum_c W[c][d]*V[c][k]
constexpr int CW_VU  = 4096;   // [32][32] VU[k'][k] = sum_c V[c][k']*U[c][k]
constexpr int CW_WG  = 5120;   // [64]     sum_c W[c][d]*gw[c]
constexpr int CW_VGX = 5184;   // [32]     sum_c V[c][k]*gw[c]
constexpr int CW_VGH = 5216;   // [32]     sum_c V[c][k]*gw[128+c]
constexpr int CW_CBU = 5248;   // [32]     sum_c b[c]*U[c][k]
constexpr int CW_CSU = 5280;   // [32]     sum_c U[c][k]
constexpr int CW_CBV = 5312;   // [32]     sum_c b[c]*V[c][k]
constexpr int CW_CSV = 5344;   // [32]     sum_c V[c][k]
constexpr int CW_SC  = 5376;   // bG = b.gw[0:128], sG = sum gw[0:128]
constexpr int CW_G   = 5384;   // [64][64] G[d][e] = sum_c W[c][d]*W[c][e]
constexpr int CW_WB  = 9480;   // [64]     wb[d] = sum_c W[c][d]*b[c]
constexpr int CW_SW  = 9544;   // [64]     sw[d] = sum_c W[c][d]
constexpr int CW_SB  = 9608;   // sb = sum b, sb2 = sum b^2
constexpr int CW_SIZE = 9610;

// workspace layout (float offsets), all fp32 except PB (double)
constexpr size_t XU_OFF  = 0;                               // NTOT*32
constexpr size_t GX_OFF  = XU_OFF + (size_t)NTOT*KK;        // NTOT
constexpr size_t YP_OFF  = GX_OFF + (size_t)NTOT;           // 1280*32
constexpr size_t PMA_OFF = YP_OFF + (size_t)YROWS*KK;       // (32*64)*40 block-contig
constexpr size_t PSA_OFF = PMA_OFF + 81920;
constexpr size_t PMB_OFF = PSA_OFF + 81920;
constexpr size_t PSB_OFF = PMB_OFF + 81920;
constexpr size_t CWS_OFF = PSB_OFF + 81920;
constexpr size_t PBN_OFF = CWS_OFF + 9612;                  // 512 double-pairs (nf)
constexpr size_t PBF_OFF = PBN_OFF + 2048;                  // 20 double-pairs (fe)
constexpr size_t IBF_OFF = PBF_OFF + 80;                    // NTOT*40 (I matrix)
}

#define ACC8(A, wv, u0, u1) do { \
  A[0] += (wv)*(u0).x; A[1] += (wv)*(u0).y; A[2] += (wv)*(u0).z; A[3] += (wv)*(u0).w; \
  A[4] += (wv)*(u1).x; A[5] += (wv)*(u1).y; A[6] += (wv)*(u1).z; A[7] += (wv)*(u1).w; } while(0)

__device__ __forceinline__ float dot4(const float4 a, const float4 b) {
  return a.x*b.x + a.y*b.y + a.z*b.z + a.w*b.w;
}
__device__ __forceinline__ float dot8v(const float x[8], const float4 y0, const float4 y1) {
  return x[0]*y0.x + x[1]*y0.y + x[2]*y0.z + x[3]*y0.w
       + x[4]*y1.x + x[5]*y1.y + x[6]*y1.z + x[7]*y1.w;
}
__device__ __forceinline__ float sigm(const float x) { return 1.f/(1.f + __expf(-x)); }

// ---------------------------------------------------------------------------
// K0: fold W/U/V/gate into small matrices (unchanged, proven).
// ---------------------------------------------------------------------------
__global__ __launch_bounds__(256)
void k_pre(const float* __restrict__ W, const float* __restrict__ b,
           const float* __restrict__ U, const float* __restrict__ V,
           const float* __restrict__ gw, float* __restrict__ CWo) {
  __shared__ float W_l[128*64];
  __shared__ float V_l[128*32];
  const int t = threadIdx.x;
  for (int f = t; f < 2048; f += 256) *(float4*)(W_l + 4*f) = *(const float4*)(W + 4*f);
  if (blockIdx.x == 0)
    for (int f = t; f < 1024; f += 256) *(float4*)(V_l + 4*f) = *(const float4*)(V + 4*f);
  __syncthreads();
  if (blockIdx.x == 1) {
    const int d = t >> 2, e0 = (t & 3) * 16;
    float g[16];
    #pragma unroll
    for (int i = 0; i < 16; ++i) g[i] = 0.f;
    for (int c = 0; c < 128; ++c) {
      const float wv = W_l[c*64 + d];
      #pragma unroll
      for (int u = 0; u < 4; ++u) {
        const float4 we = *(const float4*)(W_l + c*64 + e0 + 4*u);
        g[4*u+0] += wv*we.x; g[4*u+1] += wv*we.y;
        g[4*u+2] += wv*we.z; g[4*u+3] += wv*we.w;
      }
    }
    #pragma unroll
    for (int u = 0; u < 4; ++u)
      *(float4*)(CWo + CW_G + d*64 + e0 + 4*u) = make_float4(g[4*u],g[4*u+1],g[4*u+2],g[4*u+3]);
    if (t < 64) {
      float awb = 0.f, asw = 0.f;
      for (int c = 0; c < 128; ++c) {
        const float wv = W_l[c*64 + t];
        awb += wv * b[c]; asw += wv;
      }
      CWo[CW_WB + t] = awb; CWo[CW_SW + t] = asw;
    }
    if (t == 0) {
      float sb = 0.f, sb2 = 0.f;
      for (int c = 0; c < 128; ++c) { sb += b[c]; sb2 += b[c]*b[c]; }
      CWo[CW_SB+0] = sb; CWo[CW_SB+1] = sb2;
    }
    return;
  }
  {
    const int d = t >> 2, k0 = (t & 3) * 8;
    float au[8] = {0,0,0,0,0,0,0,0};
    float av[8] = {0,0,0,0,0,0,0,0};
    for (int c = 0; c < 128; ++c) {
      const float wv = W_l[c*64 + d];
      const float4 u0 = *(const float4*)(U + c*32 + k0);
      const float4 u1 = *(const float4*)(U + c*32 + k0 + 4);
      ACC8(au, wv, u0, u1);
      const float4 v0 = *(const float4*)(V_l + c*32 + k0);
      const float4 v1 = *(const float4*)(V_l + c*32 + k0 + 4);
      ACC8(av, wv, v0, v1);
    }
    *(float4*)(CWo + CW_WU + d*32 + k0)     = make_float4(au[0],au[1],au[2],au[3]);
    *(float4*)(CWo + CW_WU + d*32 + k0 + 4) = make_float4(au[4],au[5],au[6],au[7]);
    *(float4*)(CWo + CW_WV + d*32 + k0)     = make_float4(av[0],av[1],av[2],av[3]);
    *(float4*)(CWo + CW_WV + d*32 + k0 + 4) = make_float4(av[4],av[5],av[6],av[7]);
  }
  if (t < 128) {
    const int kp = t >> 2, k0 = (t & 3) * 8;
    float a[8] = {0,0,0,0,0,0,0,0};
    for (int c = 0; c < 128; ++c) {
      const float vv = V_l[c*32 + kp];
      const float4 u0 = *(const float4*)(U + c*32 + k0);
      const float4 u1 = *(const float4*)(U + c*32 + k0 + 4);
      ACC8(a, vv, u0, u1);
    }
    *(float4*)(CWo + CW_VU + kp*32 + k0)     = make_float4(a[0],a[1],a[2],a[3]);
    *(float4*)(CWo + CW_VU + kp*32 + k0 + 4) = make_float4(a[4],a[5],a[6],a[7]);
  }
  if (t < 64) {
    float a = 0.f;
    for (int c = 0; c < 128; ++c) a += W_l[c*64 + t] * gw[c];
    CWo[CW_WG + t] = a;
  }
  if (t < 32) {
    float a1=0,a2=0,a3=0,a4=0,a5=0,a6=0;
    for (int c = 0; c < 128; ++c) {
      const float uv = U[c*32 + t], vv = V_l[c*32 + t], bc = b[c];
      a1 += vv*gw[c]; a2 += vv*gw[128+c];
      a3 += bc*uv;    a4 += uv;
      a5 += bc*vv;    a6 += vv;
    }
    CWo[CW_VGX+t]=a1; CWo[CW_VGH+t]=a2; CWo[CW_CBU+t]=a3; CWo[CW_CSU+t]=a4;
    CWo[CW_CBV+t]=a5; CWo[CW_CSV+t]=a6;
  }
  if (t == 0) {
    float bg=0.f, sg=0.f;
    for (int c = 0; c < 128; ++c) { bg += b[c]*gw[c]; sg += gw[c]; }
    CWo[CW_SC+0]=bg; CWo[CW_SC+1]=sg;
  }
}

// ---------------------------------------------------------------------------
// K1: stats via second moments, MERGED nf+fe in one launch (532 blocks:
// 0..511 grid-stride nf, 512..531 one fe tile each). Per-block pair to PB.
// ---------------------------------------------------------------------------
__global__ __launch_bounds__(256,6)
void k_cov2(const float* __restrict__ nf, const float* __restrict__ fe,
            const float* __restrict__ CW,
            double* __restrict__ PBn, double* __restrict__ PBf) {
  __shared__ float a_l[64*64];
  __shared__ float red[12];
  const int t = threadIdx.x;
  const bool isNf = (blockIdx.x < 512);
  const float* inp = isNf ? nf : fe;
  double* PB = isNf ? PBn : PBf;
  const int bid = isNf ? blockIdx.x : (blockIdx.x - 512);
  const int ntiles = isNf ? (NTOT/64) : (YROWS/64);
  const int gstr = isNf ? 512 : 20;
  const int dg = t >> 4, eg = t & 15;
  const int d0 = dg*4, e0 = eg*4;
  float av1 = 0.f, av2 = 0.f, avb = 0.f;
  int nt = 0;
  for (int tile = bid; tile < ntiles; tile += gstr) {
    __syncthreads();
    const size_t r0 = (size_t)tile * 64;
    #pragma unroll
    for (int s = 0; s < 4; ++s) {
      int f = (t + 256*s) * 4;
      *(float4*)(a_l + f) = *(const float4*)(inp + r0*FIN + f);
    }
    __syncthreads();
    float S[4][4];
    #pragma unroll
    for (int i=0;i<4;i++)
      #pragma unroll
      for (int j=0;j<4;j++) S[i][j] = 0.f;
    float4 cs = make_float4(0.f,0.f,0.f,0.f);
    #pragma unroll 4
    for (int r = 0; r < 64; ++r) {
      const float4 ad = *(const float4*)(a_l + r*64 + d0);
      const float4 ae = *(const float4*)(a_l + r*64 + e0);
      S[0][0]+=ad.x*ae.x; S[0][1]+=ad.x*ae.y; S[0][2]+=ad.x*ae.z; S[0][3]+=ad.x*ae.w;
      S[1][0]+=ad.y*ae.x; S[1][1]+=ad.y*ae.y; S[1][2]+=ad.y*ae.z; S[1][3]+=ad.y*ae.w;
      S[2][0]+=ad.z*ae.x; S[2][1]+=ad.z*ae.y; S[2][2]+=ad.z*ae.z; S[2][3]+=ad.z*ae.w;
      S[3][0]+=ad.w*ae.x; S[3][1]+=ad.w*ae.y; S[3][2]+=ad.w*ae.z; S[3][3]+=ad.w*ae.w;
      cs.x += ad.x; cs.y += ad.y; cs.z += ad.z; cs.w += ad.w;
    }
    #pragma unroll
    for (int i = 0; i < 4; ++i) {
      const float4 g4 = *(const float4*)(CW + CW_G + (d0+i)*64 + e0);
      av2 += S[i][0]*g4.x + S[i][1]*g4.y + S[i][2]*g4.z + S[i][3]*g4.w;
    }
    if (eg == 0) {
      const float4 sw4 = *(const float4*)(CW + CW_SW + d0);
      const float4 wb4 = *(const float4*)(CW + CW_WB + d0);
      av1 += cs.x*sw4.x + cs.y*sw4.y + cs.z*sw4.z + cs.w*sw4.w;
      avb += cs.x*wb4.x + cs.y*wb4.y + cs.z*wb4.z + cs.w*wb4.w;
    }
    ++nt;
  }
  #pragma unroll
  for (int off = 32; off > 0; off >>= 1) {
    av2 += __shfl_xor(av2, off);
    av1 += __shfl_xor(av1, off);
    avb += __shfl_xor(avb, off);
  }
  const int w = t >> 6;
  if ((t & 63) == 0) { red[w*3] = av1; red[w*3+1] = av2; red[w*3+2] = avb; }
  __syncthreads();
  if (t == 0) {
    const float sb = CW[CW_SB], sb2 = CW[CW_SB+1];
    const double rowsB = 64.0 * (double)nt;
    const double s1 = (double)(red[0]+red[3]+red[6]+red[9]);
    const double s2 = (double)(red[1]+red[4]+red[7]+red[10]);
    const double sB = (double)(red[2]+red[5]+red[8]+red[11]);
    PB[(size_t)bid*2 + 0] = s1 + rowsB*(double)sb;
    PB[(size_t)bid*2 + 1] = s2 + 2.0*sB + rowsB*(double)sb2;
  }
}

// ---------------------------------------------------------------------------
// irow_compute (round-4 proven): per-lane 8 ks, 4-lane groups, xor1/2 = DPP.
// ypj layout [j][k], stride 32.
// ---------------------------------------------------------------------------
__device__ __forceinline__ void irow_compute(const float* ypj, const float xp[8],
                                             const int kq, float4 p[10]) {
  #pragma unroll
  for (int m = 0; m < 10; ++m) {
    float4 acc;
    #pragma unroll
    for (int jj = 0; jj < 4; ++jj) {
      const int j = 4*m + jj;
      const float4 y0 = *(const float4*)(ypj + j*32 + kq*8);
      const float4 y1 = *(const float4*)(ypj + j*32 + kq*8 + 4);
      const float s = xp[0]*y0.x + xp[1]*y0.y + xp[2]*y0.z + xp[3]*y0.w
                    + xp[4]*y1.x + xp[5]*y1.y + xp[6]*y1.z + xp[7]*y1.w;
      if (jj==0) acc.x = s; else if (jj==1) acc.y = s; else if (jj==2) acc.z = s; else acc.w = s;
    }
    acc.x += __shfl_xor(acc.x,1); acc.x += __shfl_xor(acc.x,2);
    acc.y += __shfl_xor(acc.y,1); acc.y += __shfl_xor(acc.y,2);
    acc.z += __shfl_xor(acc.z,1); acc.z += __shfl_xor(acc.z,2);
    acc.w += __shfl_xor(acc.w,1); acc.w += __shfl_xor(acc.w,2);
    p[m] = acc;
  }
}

// ---------------------------------------------------------------------------
// partials_out (proven; NEW block-contiguous Pm/Ps layout).
// ---------------------------------------------------------------------------
__device__ __forceinline__ void partials_out(const float4 p[10], const int t, const int kq,
    float* sredm, float* sreds, float* redm,
    float* __restrict__ PmB, float* __restrict__ PsB) {
  float ev[10];
  #pragma unroll
  for (int m = 0; m < 10; ++m) {
    const float4 qv = p[m];
    ev[m] = (kq&1) ? ((kq&2)? qv.w : qv.y) : ((kq&2)? qv.z : qv.x);
  }
  const int w = t >> 6, tl = t & 63;
  float mv[10];
  #pragma unroll
  for (int m = 0; m < 10; ++m) {
    mv[m] = ev[m];
    mv[m] = fmaxf(mv[m], __shfl_xor(mv[m], 4));
    mv[m] = fmaxf(mv[m], __shfl_xor(mv[m], 8));
    mv[m] = fmaxf(mv[m], __shfl_xor(mv[m], 16));
    mv[m] = fmaxf(mv[m], __shfl_xor(mv[m], 32));
  }
  if (tl < 4) {
    #pragma unroll
    for (int m = 0; m < 10; ++m) sredm[w*40 + 4*m + kq] = mv[m];
  }
  __syncthreads();
  if (t < 40)
    redm[t] = fmaxf(fmaxf(sredm[t], sredm[40+t]), fmaxf(sredm[80+t], sredm[120+t]));
  __syncthreads();
  float es[10];
  #pragma unroll
  for (int m = 0; m < 10; ++m) {
    const float M = redm[4*m + kq];
    es[m] = __expf(ev[m]-M);
    es[m] += __shfl_xor(es[m], 4);
    es[m] += __shfl_xor(es[m], 8);
    es[m] += __shfl_xor(es[m], 16);
    es[m] += __shfl_xor(es[m], 32);
  }
  if (tl < 4) {
    #pragma unroll
    for (int m = 0; m < 10; ++m) sreds[w*40 + 4*m + kq] = es[m];
  }
  __syncthreads();
  if (t < 40) {
    PmB[t] = redm[t];
    PsB[t] = sreds[t]+sreds[40+t]+sreds[80+t]+sreds[120+t];
  }
}

// ---------------------------------------------------------------------------
// partials_lds (proven; NEW block-contiguous Pm/Ps layout).
// ---------------------------------------------------------------------------
__device__ __forceinline__ void partials_lds(const float* p_l, const int t,
    float* sredm, float* sreds, float* redm,
    float* __restrict__ PmB, float* __restrict__ PsB) {
  const int r2 = t >> 2, kq = t & 3;
  const int w = t >> 6, tl = t & 63;
  float ev[10];
  #pragma unroll
  for (int m = 0; m < 10; ++m) ev[m] = p_l[r2*44 + 4*m + kq];
  float mv[10];
  #pragma unroll
  for (int m = 0; m < 10; ++m) {
    mv[m] = ev[m];
    mv[m] = fmaxf(mv[m], __shfl_xor(mv[m], 4));
    mv[m] = fmaxf(mv[m], __shfl_xor(mv[m], 8));
    mv[m] = fmaxf(mv[m], __shfl_xor(mv[m], 16));
    mv[m] = fmaxf(mv[m], __shfl_xor(mv[m], 32));
  }
  if (tl < 4) {
    #pragma unroll
    for (int m = 0; m < 10; ++m) sredm[w*40 + 4*m + kq] = mv[m];
  }
  __syncthreads();
  if (t < 40)
    redm[t] = fmaxf(fmaxf(sredm[t], sredm[40+t]), fmaxf(sredm[80+t], sredm[120+t]));
  __syncthreads();
  float es[10];
  #pragma unroll
  for (int m = 0; m < 10; ++m) {
    const float M = redm[4*m + kq];
    es[m] = __expf(ev[m]-M);
    es[m] += __shfl_xor(es[m], 4);
    es[m] += __shfl_xor(es[m], 8);
    es[m] += __shfl_xor(es[m], 16);
    es[m] += __shfl_xor(es[m], 32);
  }
  if (tl < 4) {
    #pragma unroll
    for (int m = 0; m < 10; ++m) sreds[w*40 + 4*m + kq] = es[m];
  }
  __syncthreads();
  if (t < 40) {
    PmB[t] = redm[t];
    PsB[t] = sreds[t]+sreds[40+t]+sreds[80+t]+sreds[120+t];
  }
}

// ---------------------------------------------------------------------------
// K2: y_p from fe, with INLINE fe-stats comb (reads PBf; k_comb eliminated).
// ---------------------------------------------------------------------------
__global__ __launch_bounds__(256,4)
void k_yp3(const float* __restrict__ fe, const float* __restrict__ CW,
           const float* __restrict__ q, const double* __restrict__ PBf,
           float* __restrict__ yp) {
  __shared__ float in_t[64*64];
  __shared__ float Wl[64*32];
  __shared__ double fred[2];
  const int t = threadIdx.x;
  const int r0 = blockIdx.x * 64;
  #pragma unroll
  for (int s = 0; s < 4; ++s) {
    int f = (t + 256*s) * 4;
    int r = f >> 6, d = f & 63;
    float4 v = *(const float4*)(fe + (size_t)r0*FIN + f);
    *(float4*)(in_t + r*64 + (d ^ ((r & 7) * 8))) = v;
  }
  #pragma unroll
  for (int s = 0; s < 2; ++s) {
    int f = (t + 256*s) * 4;
    *(float4*)(Wl + f) = *(const float4*)(CW + CW_WV + f);
  }
  if (t < 64) {                          // inline comb (k_comb fe order)
    double c = (t < 20) ? PBf[2*t]   : 0.0;
    double d = (t < 20) ? PBf[2*t+1] : 0.0;
    #pragma unroll
    for (int off = 32; off > 0; off >>= 1) {
      c += __shfl_down(c, off);
      d += __shfl_down(d, off);
    }
    if (t == 0) { fred[0] = c; fred[1] = d; }
  }
  __syncthreads();
  const double cy = (double)YROWS * (double)C;
  const double myd = fred[0]/cy, vy = fred[1]/cy - myd*myd;
  const float ry = (float)(1.0/sqrt(vy + (double)EPS));
  const float mr = (float)myd * ry;
  const int r2 = t >> 2, kq = t & 3;
  const int swz = (r2 & 7) * 8;
  float acc[8] = {0,0,0,0,0,0,0,0};
  #pragma unroll
  for (int dc = 0; dc < 16; ++dc) {
    const int d = dc*4;
    const float4 a = *(const float4*)(in_t + r2*64 + (d ^ swz));
    { const float4 w0 = *(const float4*)(Wl + (d+0)*32 + kq*8);
      const float4 w1 = *(const float4*)(Wl + (d+0)*32 + kq*8 + 4); ACC8(acc, a.x, w0, w1); }
    { const float4 w0 = *(const float4*)(Wl + (d+1)*32 + kq*8);
      const float4 w1 = *(const float4*)(Wl + (d+1)*32 + kq*8 + 4); ACC8(acc, a.y, w0, w1); }
    { const float4 w0 = *(const float4*)(Wl + (d+2)*32 + kq*8);
      const float4 w1 = *(const float4*)(Wl + (d+2)*32 + kq*8 + 4); ACC8(acc, a.z, w0, w1); }
    { const float4 w0 = *(const float4*)(Wl + (d+3)*32 + kq*8);
      const float4 w1 = *(const float4*)(Wl + (d+3)*32 + kq*8 + 4); ACC8(acc, a.w, w0, w1); }
  }
  #pragma unroll
  for (int i = 0; i < 8; ++i) {
    const int k = kq*8 + i;
    const float typ = ry*(acc[i] + CW[CW_CBV+k]) - mr*CW[CW_CSV+k];
    float v = fmaxf(typ, 0.f);
    acc[i] = fmaxf(q[k]*v, 0.f);
  }
  *(float4*)(yp + (size_t)(r0+r2)*KK + kq*8)     = make_float4(acc[0],acc[1],acc[2],acc[3]);
  *(float4*)(yp + (size_t)(r0+r2)*KK + kq*8 + 4) = make_float4(acc[4],acc[5],acc[6],acc[7]);
}

// ---------------------------------------------------------------------------
// K3: layer-0 with INLINE nf-stats comb (reads PBn). 4-row blocked GEMM,
// streamed I-row -> p_l -> partials (contig layout) -> coalesced I write.
// ---------------------------------------------------------------------------
__global__ __launch_bounds__(256,4)
void k_I0c(const float* __restrict__ nf, const float* __restrict__ CW,
           const double* __restrict__ PBn, const float* __restrict__ yp,
           float* __restrict__ XU, float* __restrict__ GX,
           float* __restrict__ Pm, float* __restrict__ Ps,
           float* __restrict__ Ibf) {
  __shared__ __align__(16) float in_t[64*68];   // overlaid by p_l (64*44) later
  __shared__ __align__(16) float Wl[64*36];     // row d -> (d&15)*4 + (d>>4)
  __shared__ __align__(16) float ypj[40*40];
  __shared__ __align__(16) float wgl[64];
  __shared__ float sredm[160], sreds[160], redm[40];
  __shared__ double dred[8];
  float* p_l = in_t;
  const int t = threadIdx.x;
  const int bid = blockIdx.x;
  const int b = bid >> 6, blk = bid & 63;
  const size_t rowbase = (size_t)b*NPG + (size_t)blk*64;
  #pragma unroll
  for (int s = 0; s < 4; ++s) {
    int f = (t + 256*s) * 4;
    int r = f >> 6, d = f & 63;
    *(float4*)(in_t + r*68 + d) = *(const float4*)(nf + rowbase*FIN + f);
  }
  #pragma unroll
  for (int s = 0; s < 2; ++s) {
    int idx = t + 256*s;
    int d = idx >> 3, kc = idx & 7;
    *(float4*)(Wl + ((d&15)*4 + (d>>4))*36 + kc*4) = *(const float4*)(CW + CW_WU + idx*4);
  }
  for (int f4v = t; f4v < 320; f4v += 256) {
    int j = f4v >> 3, kc = f4v & 7;
    *(float4*)(ypj + j*40 + kc*4) = *(const float4*)(yp + (size_t)b*(JJ*KK) + f4v*4);
  }
  if (t < 64) wgl[t] = CW[CW_WG + t];
  {                                      // inline comb (k_comb nf order)
    double a = PBn[2*t] + PBn[2*(t+256)];
    double bb = PBn[2*t+1] + PBn[2*(t+256)+1];
    #pragma unroll
    for (int off = 32; off > 0; off >>= 1) {
      a  += __shfl_down(a, off);
      bb += __shfl_down(bb, off);
    }
    if ((t & 63) == 0) { dred[(t>>6)*2] = a; dred[(t>>6)*2+1] = bb; }
  }
  __syncthreads();
  const double ST0 = dred[0]+dred[2]+dred[4]+dred[6];
  const double ST1 = dred[1]+dred[3]+dred[5]+dred[7];
  const double cx = (double)NTOT * (double)C;
  const double mx = ST0/cx, vx = ST1/cx - mx*mx;
  const float rx = (float)(1.0/sqrt(vx + (double)EPS));
  const float mr = (float)mx * rx;
  const int kq = t & 3, X = (t >> 2) & 3, rr = t >> 4;
  float acc[4][8];
  #pragma unroll
  for (int i=0;i<4;i++)
    #pragma unroll
    for (int u=0;u<8;u++) acc[i][u] = 0.f;
  #pragma unroll
  for (int dd = 0; dd < 4; ++dd) {
    float4 a4[4];
    #pragma unroll
    for (int i = 0; i < 4; ++i)
      a4[i] = *(const float4*)(in_t + (rr+16*i)*68 + X*16 + dd*4);
    #pragma unroll
    for (int qd = 0; qd < 4; ++qd) {
      const int lrow = (dd*4 + qd)*4 + X;
      const float4 w0 = *(const float4*)(Wl + lrow*36 + kq*8);
      const float4 w1 = *(const float4*)(Wl + lrow*36 + kq*8 + 4);
      #pragma unroll
      for (int i = 0; i < 4; ++i) {
        const float av = (qd==0)? a4[i].x : (qd==1)? a4[i].y : (qd==2)? a4[i].z : a4[i].w;
        ACC8(acc[i], av, w0, w1);
      }
    }
  }
  #pragma unroll
  for (int i = 0; i < 4; ++i)
    #pragma unroll
    for (int u = 0; u < 8; ++u) {
      acc[i][u] += __shfl_xor(acc[i][u], 4);
      acc[i][u] += __shfl_xor(acc[i][u], 8);
    }
  float gp[4];
  #pragma unroll
  for (int i = 0; i < 4; ++i) {
    const float4 a = *(const float4*)(in_t + (rr+16*i)*68 + X*16 + kq*4);
    const float4 w = *(const float4*)(wgl + X*16 + kq*4);
    gp[i] = dot4(a, w);
    gp[i] += __shfl_xor(gp[i], 1);
    gp[i] += __shfl_xor(gp[i], 2);
    gp[i] += __shfl_xor(gp[i], 4);
    gp[i] += __shfl_xor(gp[i], 8);
  }
  const float4 cb0 = *(const float4*)(CW + CW_CBU + kq*8);
  const float4 cb1 = *(const float4*)(CW + CW_CBU + kq*8 + 4);
  const float4 cu0 = *(const float4*)(CW + CW_CSU + kq*8);
  const float4 cu1 = *(const float4*)(CW + CW_CSU + kq*8 + 4);
  float xp[4][8];
  #pragma unroll
  for (int i = 0; i < 4; ++i) {
    acc[i][0] = rx*(acc[i][0] + cb0.x) - mr*cu0.x;
    acc[i][1] = rx*(acc[i][1] + cb0.y) - mr*cu0.y;
    acc[i][2] = rx*(acc[i][2] + cb0.z) - mr*cu0.z;
    acc[i][3] = rx*(acc[i][3] + cb0.w) - mr*cu0.w;
    acc[i][4] = rx*(acc[i][4] + cb1.x) - mr*cu1.x;
    acc[i][5] = rx*(acc[i][5] + cb1.y) - mr*cu1.y;
    acc[i][6] = rx*(acc[i][6] + cb1.z) - mr*cu1.z;
    acc[i][7] = rx*(acc[i][7] + cb1.w) - mr*cu1.w;
    #pragma unroll
    for (int u = 0; u < 8; ++u) xp[i][u] = fmaxf(acc[i][u], 0.f);
  }
  if (X == 0) {
    const float bG = CW[CW_SC], sG = CW[CW_SC+1];
    #pragma unroll
    for (int i = 0; i < 4; ++i) {
      const size_t row = rowbase + rr + 16*i;
      *(float4*)(XU + row*KK + kq*8)     = make_float4(acc[i][0],acc[i][1],acc[i][2],acc[i][3]);
      *(float4*)(XU + row*KK + kq*8 + 4) = make_float4(acc[i][4],acc[i][5],acc[i][6],acc[i][7]);
      if (kq == 0) GX[row] = rx*(gp[i] + bG) - mr*sG;
    }
  }
  __syncthreads();                       // all in_t reads done; overlay p_l
  #pragma unroll 2
  for (int jj = 0; jj < 10; ++jj) {
    const int j = X*10 + jj;
    const float4 y0 = *(const float4*)(ypj + j*40 + kq*8);
    const float4 y1 = *(const float4*)(ypj + j*40 + kq*8 + 4);
    float p4[4];
    #pragma unroll
    for (int i = 0; i < 4; ++i) p4[i] = dot8v(xp[i], y0, y1);
    #pragma unroll
    for (int i = 0; i < 4; ++i) {
      p4[i] += __shfl_xor(p4[i], 1);
      p4[i] += __shfl_xor(p4[i], 2);
    }
    if (kq == 0) {
      #pragma unroll
      for (int i = 0; i < 4; ++i)
        p_l[(rr+16*i)*44 + j] = p4[i];
    }
  }
  __syncthreads();
  partials_lds(p_l, t, sredm, sreds, redm,
               Pm + ((size_t)b*64 + blk)*40, Ps + ((size_t)b*64 + blk)*40);
  // I write (p_l untouched by partials_lds; coalesced f4)
  for (int f4v = t; f4v < 640; f4v += 256) {
    const int row = f4v / 10, jq = f4v - row*10;
    *(float4*)(Ibf + (rowbase+row)*JJ + jq*4) = *(const float4*)(p_l + row*44 + jq*4);
  }
}

// ---------------------------------------------------------------------------
// K4: fused layer update with INLINE softmax comb (k_comb2 order) and
// transposed e-tile (stride 65, conflict-free phase-B column reads).
// ---------------------------------------------------------------------------
template<int FINAL>
__global__ __launch_bounds__(256,4)
void k_fused7(float* __restrict__ XU, float* __restrict__ GX,
              float* __restrict__ Ibf,
              const float* __restrict__ yp, const float* __restrict__ CW,
              const float* __restrict__ gb,
              const float* __restrict__ PmIn, const float* __restrict__ PsIn,
              float* __restrict__ PmOut, float* __restrict__ PsOut,
              float* __restrict__ outp) {
  __shared__ float ypj[40*32];
  __shared__ float eT[40*65];            // e transposed; sred overlay later
  __shared__ float h_l[64*40];
  __shared__ float VUl[32*32];
  __shared__ float M_l[40], Si_l[40];
  __shared__ float vgxl[32], vghl[32];
  __shared__ float Mq[160], Sq[160];
  float* sredm = eT;
  float* sreds = eT + 160;
  float* redm  = eT + 320;
  const int t = threadIdx.x;
  const int bid = blockIdx.x;
  const int b = bid >> 6, blk = bid & 63;
  const size_t rowbase = (size_t)b*NPG + (size_t)blk*64;
  for (int f4v = t; f4v < 320; f4v += 256)
    *(float4*)(ypj + f4v*4) = *(const float4*)(yp + (size_t)b*(JJ*KK) + f4v*4);
  { const int f = t*4;
    *(float4*)(VUl + f) = *(const float4*)(CW + CW_VU + f); }
  if (t < 32) { vgxl[t] = CW[CW_VGX+t]; vghl[t] = CW[CW_VGH+t]; }
  // inline comb (k_comb2 order) on block-contiguous partials
  const int j160 = t >> 2, q160 = t & 3;
  float pmv[16];
  if (t < 160) {
    float m = 0.f;
    #pragma unroll
    for (int u = 0; u < 16; ++u) {
      pmv[u] = PmIn[((size_t)b*64 + q160*16 + u)*40 + j160];
      m = fmaxf(m, pmv[u]);
    }
    Mq[t] = m;
  }
  __syncthreads();
  if (t < 40) M_l[t] = fmaxf(fmaxf(Mq[4*t], Mq[4*t+1]), fmaxf(Mq[4*t+2], Mq[4*t+3]));
  __syncthreads();
  if (t < 160) {
    const float M = M_l[j160];
    float s = 0.f;
    #pragma unroll
    for (int u = 0; u < 16; ++u)
      s += PsIn[((size_t)b*64 + q160*16 + u)*40 + j160] * __expf(pmv[u] - M);
    Sq[t] = s;
  }
  __syncthreads();
  if (t < 40) Si_l[t] = 1.f/(Sq[4*t] + Sq[4*t+1] + Sq[4*t+2] + Sq[4*t+3]);
  __syncthreads();
  // e staging from Ibf, TRANSPOSED: eT[j][row], stride 65
  for (int f4v = t; f4v < 640; f4v += 256) {
    const int row = f4v / 10, jq = f4v - row*10;
    const float4 iv = *(const float4*)(Ibf + (rowbase+row)*JJ + jq*4);
    eT[(jq*4+0)*65 + row] = __expf(iv.x - M_l[jq*4+0]) * Si_l[jq*4+0];
    eT[(jq*4+1)*65 + row] = __expf(iv.y - M_l[jq*4+1]) * Si_l[jq*4+1];
    eT[(jq*4+2)*65 + row] = __expf(iv.z - M_l[jq*4+2]) * Si_l[jq*4+2];
    eT[(jq*4+3)*65 + row] = __expf(iv.w - M_l[jq*4+3]) * Si_l[jq*4+3];
  }
  const int r2 = t >> 2, kq = t & 3;
  float xu[8];
  {
    const float4 x0 = *(const float4*)(XU + (rowbase+r2)*KK + kq*8);
    const float4 x1 = *(const float4*)(XU + (rowbase+r2)*KK + kq*8 + 4);
    xu[0]=x0.x; xu[1]=x0.y; xu[2]=x0.z; xu[3]=x0.w;
    xu[4]=x1.x; xu[5]=x1.y; xu[6]=x1.z; xu[7]=x1.w;
  }
  const float gx = GX[rowbase + r2];
  __syncthreads();
  // phase B: h[n][k] = relu(sum_j A[n][j]*yp[j][k]) — conflict-free e reads
  {
    const int rq = t >> 3, kc = t & 7;
    float4 h0 = make_float4(0.f,0.f,0.f,0.f), h1 = make_float4(0.f,0.f,0.f,0.f);
    #pragma unroll 4
    for (int j = 0; j < JJ; ++j) {
      const float4 yv = *(const float4*)(ypj + j*32 + kc*4);
      const float e0 = eT[j*65 + rq];
      const float e1 = eT[j*65 + rq + 32];
      h0.x += e0*yv.x; h0.y += e0*yv.y; h0.z += e0*yv.z; h0.w += e0*yv.w;
      h1.x += e1*yv.x; h1.y += e1*yv.y; h1.z += e1*yv.z; h1.w += e1*yv.w;
    }
    h0.x = fmaxf(h0.x,0.f); h0.y = fmaxf(h0.y,0.f); h0.z = fmaxf(h0.z,0.f); h0.w = fmaxf(h0.w,0.f);
    h1.x = fmaxf(h1.x,0.f); h1.y = fmaxf(h1.y,0.f); h1.z = fmaxf(h1.z,0.f); h1.w = fmaxf(h1.w,0.f);
    *(float4*)(h_l + rq*40 + kc*4) = h0;
    *(float4*)(h_l + (rq+32)*40 + kc*4) = h1;
  }
  __syncthreads();
  // phase C: hu = h@VU, gate, blend in K-space
  float hu[8] = {0,0,0,0,0,0,0,0};
  float gh2 = 0.f, ghx = 0.f;
  #pragma unroll 8
  for (int kp = 0; kp < KK; ++kp) {
    const float hv = h_l[r2*40 + kp];
    gh2 += hv * vghl[kp];
    ghx += hv * vgxl[kp];
    const float4 v0 = *(const float4*)(VUl + kp*32 + kq*8);
    const float4 v1 = *(const float4*)(VUl + kp*32 + kq*8 + 4);
    ACC8(hu, hv, v0, v1);
  }
  const float z = 1.f/(1.f + __expf(-(gx + gh2 + gb[0])));
  float xp[8];
  #pragma unroll
  for (int i = 0; i < 8; ++i) {
    xu[i] = (1.f - z)*xu[i] + z*hu[i];
    xp[i] = fmaxf(xu[i], 0.f);
  }
  if (!FINAL) {
    *(float4*)(XU + (rowbase+r2)*KK + kq*8)     = make_float4(xu[0],xu[1],xu[2],xu[3]);
    *(float4*)(XU + (rowbase+r2)*KK + kq*8 + 4) = make_float4(xu[4],xu[5],xu[6],xu[7]);
    if (kq == 0) GX[rowbase + r2] = (1.f - z)*gx + z*ghx;
  }
  // single irow on updated xp
  float4 p[10];
  irow_compute(ypj, xp, kq, p);
  if (FINAL) {
    float s = 0.f;
    #pragma unroll
    for (int m = 0; m < 10; ++m)
      s += p[m].x*p[m].x + p[m].y*p[m].y + p[m].z*p[m].z + p[m].w*p[m].w;
    if (kq == 0) outp[rowbase + r2] = 1.f/(1.f + __expf(-s));
    return;
  }
  // I write: lane kq stores m with (m&3)==kq (full row covered across 4 lanes)
  #pragma unroll
  for (int m = 0; m < 10; ++m)
    if ((m & 3) == kq)
      *(float4*)(Ibf + (rowbase+r2)*JJ + 4*m) = p[m];
  partials_out(p, t, kq, sredm, sreds, redm,
               PmOut + ((size_t)b*64 + blk)*40, PsOut + ((size_t)b*64 + blk)*40);
}

extern "C" void kernel_launch(void* const* d_in, const int* in_sizes, int n_in,
                              void* d_out, int out_size, void* d_ws, size_t ws_size,
                              hipStream_t stream) {
  const float* nf  = (const float*)d_in[0];
  const float* fe  = (const float*)d_in[1];
  const float* W   = (const float*)d_in[2];
  const float* bin = (const float*)d_in[3];
  const float* U   = (const float*)d_in[4];
  const float* V   = (const float*)d_in[5];
  const float* q   = (const float*)d_in[6];
  const float* gw  = (const float*)d_in[7];
  const float* gb  = (const float*)d_in[8];
  float* out = (float*)d_out;
  float* wf  = (float*)d_ws;

  float* XU  = wf + XU_OFF;
  float* GX  = wf + GX_OFF;
  float* YP  = wf + YP_OFF;
  float* PMa = wf + PMA_OFF;
  float* PSa = wf + PSA_OFF;
  float* PMb = wf + PMB_OFF;
  float* PSb = wf + PSB_OFF;
  float* CWp = wf + CWS_OFF;
  float* IBF = wf + IBF_OFF;
  double* PBn = (double*)(wf + PBN_OFF);
  double* PBf = (double*)(wf + PBF_OFF);

  k_pre<<<2, 256, 0, stream>>>(W, bin, U, V, gw, CWp);
  k_cov2<<<532, 256, 0, stream>>>(nf, fe, CWp, PBn, PBf);
  k_yp3<<<YROWS/64, 256, 0, stream>>>(fe, CWp, q, PBf, YP);
  k_I0c<<<NTOT/64, 256, 0, stream>>>(nf, CWp, PBn, YP, XU, GX, PMa, PSa, IBF);
  k_fused7<0><<<NTOT/64, 256, 0, stream>>>(XU, GX, IBF, YP, CWp, gb, PMa, PSa, PMb, PSb, nullptr);
  k_fused7<1><<<NTOT/64, 256, 0, stream>>>(XU, GX, IBF, YP, CWp, gb, PMb, PSb, nullptr, nullptr, out);
}

// Round 11
// 244.977 us; speedup vs baseline: 1.3767x; 1.0168x over previous
//
#include <hip/hip_runtime.h>
#include <math.h>

namespace {
constexpr int BB = 32, NPG = 4096, NTOT = BB*NPG, C = 128, FIN = 64, KK = 32, JJ = 40;
constexpr int YROWS = BB*JJ; // 1280
constexpr float EPS = 1e-5f;

// CW (precomputed folded constants) float offsets
constexpr int CW_WU  = 0;      // [64][32] Wu[d][k] = sum_c W[c][d]*U[c][k]
constexpr int CW_WV  = 2048;   // [64][32] Wv[d][k] = sum_c W[c][d]*V[c][k]
constexpr int CW_VU  = 4096;   // [32][32] VU[k'][k] = sum_c V[c][k']*U[c][k]
constexpr int CW_WG  = 5120;   // [64]     sum_c W[c][d]*gw[c]
constexpr int CW_VGX = 5184;   // [32]     sum_c V[c][k]*gw[c]
constexpr int CW_VGH = 5216;   // [32]     sum_c V[c][k]*gw[128+c]
constexpr int CW_CBU = 5248;   // [32]     sum_c b[c]*U[c][k]
constexpr int CW_CSU = 5280;   // [32]     sum_c U[c][k]
constexpr int CW_CBV = 5312;   // [32]     sum_c b[c]*V[c][k]
constexpr int CW_CSV = 5344;   // [32]     sum_c V[c][k]
constexpr int CW_SC  = 5376;   // bG = b.gw[0:128], sG = sum gw[0:128]
constexpr int CW_G   = 5384;   // [64][64] G[d][e] = sum_c W[c][d]*W[c][e]
constexpr int CW_WB  = 9480;   // [64]     wb[d] = sum_c W[c][d]*b[c]
constexpr int CW_SW  = 9544;   // [64]     sw[d] = sum_c W[c][d]
constexpr int CW_SB  = 9608;   // sb = sum b, sb2 = sum b^2
constexpr int CW_SIZE = 9610;

// workspace layout (float offsets), all fp32 except PB (double)
constexpr size_t XU_OFF  = 0;                               // NTOT*32
constexpr size_t GX_OFF  = XU_OFF + (size_t)NTOT*KK;        // NTOT
constexpr size_t YP_OFF  = GX_OFF + (size_t)NTOT;           // 1280*32
constexpr size_t PMA_OFF = YP_OFF + (size_t)YROWS*KK;       // (32*64)*40 block-contig
constexpr size_t PSA_OFF = PMA_OFF + 81920;
constexpr size_t PMB_OFF = PSA_OFF + 81920;
constexpr size_t PSB_OFF = PMB_OFF + 81920;
constexpr size_t CWS_OFF = PSB_OFF + 81920;
constexpr size_t PBN_OFF = CWS_OFF + 9612;                  // 2048 double-pairs (nf)
constexpr size_t PBF_OFF = PBN_OFF + 8192;                  // 20 double-pairs (fe)
constexpr size_t IBF_OFF = PBF_OFF + 80;                    // NTOT*40 (I matrix)
}

#define ACC8(A, wv, u0, u1) do { \
  A[0] += (wv)*(u0).x; A[1] += (wv)*(u0).y; A[2] += (wv)*(u0).z; A[3] += (wv)*(u0).w; \
  A[4] += (wv)*(u1).x; A[5] += (wv)*(u1).y; A[6] += (wv)*(u1).z; A[7] += (wv)*(u1).w; } while(0)

__device__ __forceinline__ float dot4(const float4 a, const float4 b) {
  return a.x*b.x + a.y*b.y + a.z*b.z + a.w*b.w;
}
__device__ __forceinline__ float dot8v(const float x[8], const float4 y0, const float4 y1) {
  return x[0]*y0.x + x[1]*y0.y + x[2]*y0.z + x[3]*y0.w
       + x[4]*y1.x + x[5]*y1.y + x[6]*y1.z + x[7]*y1.w;
}
__device__ __forceinline__ float sigm(const float x) { return 1.f/(1.f + __expf(-x)); }

// ---------------------------------------------------------------------------
// K0: fold W/U/V/gate into small matrices (unchanged, proven).
// ---------------------------------------------------------------------------
__global__ __launch_bounds__(256)
void k_pre(const float* __restrict__ W, const float* __restrict__ b,
           const float* __restrict__ U, const float* __restrict__ V,
           const float* __restrict__ gw, float* __restrict__ CWo) {
  __shared__ float W_l[128*64];
  __shared__ float V_l[128*32];
  const int t = threadIdx.x;
  for (int f = t; f < 2048; f += 256) *(float4*)(W_l + 4*f) = *(const float4*)(W + 4*f);
  if (blockIdx.x == 0)
    for (int f = t; f < 1024; f += 256) *(float4*)(V_l + 4*f) = *(const float4*)(V + 4*f);
  __syncthreads();
  if (blockIdx.x == 1) {
    const int d = t >> 2, e0 = (t & 3) * 16;
    float g[16];
    #pragma unroll
    for (int i = 0; i < 16; ++i) g[i] = 0.f;
    for (int c = 0; c < 128; ++c) {
      const float wv = W_l[c*64 + d];
      #pragma unroll
      for (int u = 0; u < 4; ++u) {
        const float4 we = *(const float4*)(W_l + c*64 + e0 + 4*u);
        g[4*u+0] += wv*we.x; g[4*u+1] += wv*we.y;
        g[4*u+2] += wv*we.z; g[4*u+3] += wv*we.w;
      }
    }
    #pragma unroll
    for (int u = 0; u < 4; ++u)
      *(float4*)(CWo + CW_G + d*64 + e0 + 4*u) = make_float4(g[4*u],g[4*u+1],g[4*u+2],g[4*u+3]);
    if (t < 64) {
      float awb = 0.f, asw = 0.f;
      for (int c = 0; c < 128; ++c) {
        const float wv = W_l[c*64 + t];
        awb += wv * b[c]; asw += wv;
      }
      CWo[CW_WB + t] = awb; CWo[CW_SW + t] = asw;
    }
    if (t == 0) {
      float sb = 0.f, sb2 = 0.f;
      for (int c = 0; c < 128; ++c) { sb += b[c]; sb2 += b[c]*b[c]; }
      CWo[CW_SB+0] = sb; CWo[CW_SB+1] = sb2;
    }
    return;
  }
  {
    const int d = t >> 2, k0 = (t & 3) * 8;
    float au[8] = {0,0,0,0,0,0,0,0};
    float av[8] = {0,0,0,0,0,0,0,0};
    for (int c = 0; c < 128; ++c) {
      const float wv = W_l[c*64 + d];
      const float4 u0 = *(const float4*)(U + c*32 + k0);
      const float4 u1 = *(const float4*)(U + c*32 + k0 + 4);
      ACC8(au, wv, u0, u1);
      const float4 v0 = *(const float4*)(V_l + c*32 + k0);
      const float4 v1 = *(const float4*)(V_l + c*32 + k0 + 4);
      ACC8(av, wv, v0, v1);
    }
    *(float4*)(CWo + CW_WU + d*32 + k0)     = make_float4(au[0],au[1],au[2],au[3]);
    *(float4*)(CWo + CW_WU + d*32 + k0 + 4) = make_float4(au[4],au[5],au[6],au[7]);
    *(float4*)(CWo + CW_WV + d*32 + k0)     = make_float4(av[0],av[1],av[2],av[3]);
    *(float4*)(CWo + CW_WV + d*32 + k0 + 4) = make_float4(av[4],av[5],av[6],av[7]);
  }
  if (t < 128) {
    const int kp = t >> 2, k0 = (t & 3) * 8;
    float a[8] = {0,0,0,0,0,0,0,0};
    for (int c = 0; c < 128; ++c) {
      const float vv = V_l[c*32 + kp];
      const float4 u0 = *(const float4*)(U + c*32 + k0);
      const float4 u1 = *(const float4*)(U + c*32 + k0 + 4);
      ACC8(a, vv, u0, u1);
    }
    *(float4*)(CWo + CW_VU + kp*32 + k0)     = make_float4(a[0],a[1],a[2],a[3]);
    *(float4*)(CWo + CW_VU + kp*32 + k0 + 4) = make_float4(a[4],a[5],a[6],a[7]);
  }
  if (t < 64) {
    float a = 0.f;
    for (int c = 0; c < 128; ++c) a += W_l[c*64 + t] * gw[c];
    CWo[CW_WG + t] = a;
  }
  if (t < 32) {
    float a1=0,a2=0,a3=0,a4=0,a5=0,a6=0;
    for (int c = 0; c < 128; ++c) {
      const float uv = U[c*32 + t], vv = V_l[c*32 + t], bc = b[c];
      a1 += vv*gw[c]; a2 += vv*gw[128+c];
      a3 += bc*uv;    a4 += uv;
      a5 += bc*vv;    a6 += vv;
    }
    CWo[CW_VGX+t]=a1; CWo[CW_VGH+t]=a2; CWo[CW_CBU+t]=a3; CWo[CW_CSU+t]=a4;
    CWo[CW_CBV+t]=a5; CWo[CW_CSV+t]=a6;
  }
  if (t == 0) {
    float bg=0.f, sg=0.f;
    for (int c = 0; c < 128; ++c) { bg += b[c]*gw[c]; sg += gw[c]; }
    CWo[CW_SC+0]=bg; CWo[CW_SC+1]=sg;
  }
}

// ---------------------------------------------------------------------------
// K1: stats via second moments. FULL-PARALLEL grid: 2048 nf blocks (1 tile
// each) + 20 fe blocks. Round-3's 512-block grid-stride starved occupancy
// (2 blocks/CU) and made this the hidden-largest kernel (~90us).
// ---------------------------------------------------------------------------
__global__ __launch_bounds__(256,6)
void k_cov2(const float* __restrict__ nf, const float* __restrict__ fe,
            const float* __restrict__ CW,
            double* __restrict__ PBn, double* __restrict__ PBf) {
  __shared__ float a_l[64*64];
  __shared__ float red[12];
  const int t = threadIdx.x;
  const bool isNf = (blockIdx.x < 2048);
  const float* inp = isNf ? nf : fe;
  double* PB = isNf ? PBn : PBf;
  const int bid = isNf ? blockIdx.x : (blockIdx.x - 2048);
  const int dg = t >> 4, eg = t & 15;
  const int d0 = dg*4, e0 = eg*4;
  float av1 = 0.f, av2 = 0.f, avb = 0.f;
  {
    const size_t r0 = (size_t)bid * 64;
    #pragma unroll
    for (int s = 0; s < 4; ++s) {
      int f = (t + 256*s) * 4;
      *(float4*)(a_l + f) = *(const float4*)(inp + r0*FIN + f);
    }
    __syncthreads();
    float S[4][4];
    #pragma unroll
    for (int i=0;i<4;i++)
      #pragma unroll
      for (int j=0;j<4;j++) S[i][j] = 0.f;
    float4 cs = make_float4(0.f,0.f,0.f,0.f);
    #pragma unroll 4
    for (int r = 0; r < 64; ++r) {
      const float4 ad = *(const float4*)(a_l + r*64 + d0);
      const float4 ae = *(const float4*)(a_l + r*64 + e0);
      S[0][0]+=ad.x*ae.x; S[0][1]+=ad.x*ae.y; S[0][2]+=ad.x*ae.z; S[0][3]+=ad.x*ae.w;
      S[1][0]+=ad.y*ae.x; S[1][1]+=ad.y*ae.y; S[1][2]+=ad.y*ae.z; S[1][3]+=ad.y*ae.w;
      S[2][0]+=ad.z*ae.x; S[2][1]+=ad.z*ae.y; S[2][2]+=ad.z*ae.z; S[2][3]+=ad.z*ae.w;
      S[3][0]+=ad.w*ae.x; S[3][1]+=ad.w*ae.y; S[3][2]+=ad.w*ae.z; S[3][3]+=ad.w*ae.w;
      cs.x += ad.x; cs.y += ad.y; cs.z += ad.z; cs.w += ad.w;
    }
    #pragma unroll
    for (int i = 0; i < 4; ++i) {
      const float4 g4 = *(const float4*)(CW + CW_G + (d0+i)*64 + e0);
      av2 += S[i][0]*g4.x + S[i][1]*g4.y + S[i][2]*g4.z + S[i][3]*g4.w;
    }
    if (eg == 0) {
      const float4 sw4 = *(const float4*)(CW + CW_SW + d0);
      const float4 wb4 = *(const float4*)(CW + CW_WB + d0);
      av1 += cs.x*sw4.x + cs.y*sw4.y + cs.z*sw4.z + cs.w*sw4.w;
      avb += cs.x*wb4.x + cs.y*wb4.y + cs.z*wb4.z + cs.w*wb4.w;
    }
  }
  #pragma unroll
  for (int off = 32; off > 0; off >>= 1) {
    av2 += __shfl_xor(av2, off);
    av1 += __shfl_xor(av1, off);
    avb += __shfl_xor(avb, off);
  }
  const int w = t >> 6;
  if ((t & 63) == 0) { red[w*3] = av1; red[w*3+1] = av2; red[w*3+2] = avb; }
  __syncthreads();
  if (t == 0) {
    const float sb = CW[CW_SB], sb2 = CW[CW_SB+1];
    const double rowsB = 64.0;
    const double s1 = (double)(red[0]+red[3]+red[6]+red[9]);
    const double s2 = (double)(red[1]+red[4]+red[7]+red[10]);
    const double sB = (double)(red[2]+red[5]+red[8]+red[11]);
    PB[(size_t)bid*2 + 0] = s1 + rowsB*(double)sb;
    PB[(size_t)bid*2 + 1] = s2 + 2.0*sB + rowsB*(double)sb2;
  }
}

// ---------------------------------------------------------------------------
// irow_compute (round-4 proven): per-lane 8 ks, 4-lane groups, xor1/2 = DPP.
// ypj layout [j][k], stride 32.
// ---------------------------------------------------------------------------
__device__ __forceinline__ void irow_compute(const float* ypj, const float xp[8],
                                             const int kq, float4 p[10]) {
  #pragma unroll
  for (int m = 0; m < 10; ++m) {
    float4 acc;
    #pragma unroll
    for (int jj = 0; jj < 4; ++jj) {
      const int j = 4*m + jj;
      const float4 y0 = *(const float4*)(ypj + j*32 + kq*8);
      const float4 y1 = *(const float4*)(ypj + j*32 + kq*8 + 4);
      const float s = xp[0]*y0.x + xp[1]*y0.y + xp[2]*y0.z + xp[3]*y0.w
                    + xp[4]*y1.x + xp[5]*y1.y + xp[6]*y1.z + xp[7]*y1.w;
      if (jj==0) acc.x = s; else if (jj==1) acc.y = s; else if (jj==2) acc.z = s; else acc.w = s;
    }
    acc.x += __shfl_xor(acc.x,1); acc.x += __shfl_xor(acc.x,2);
    acc.y += __shfl_xor(acc.y,1); acc.y += __shfl_xor(acc.y,2);
    acc.z += __shfl_xor(acc.z,1); acc.z += __shfl_xor(acc.z,2);
    acc.w += __shfl_xor(acc.w,1); acc.w += __shfl_xor(acc.w,2);
    p[m] = acc;
  }
}

// ---------------------------------------------------------------------------
// partials_out (proven; block-contiguous Pm/Ps layout).
// ---------------------------------------------------------------------------
__device__ __forceinline__ void partials_out(const float4 p[10], const int t, const int kq,
    float* sredm, float* sreds, float* redm,
    float* __restrict__ PmB, float* __restrict__ PsB) {
  float ev[10];
  #pragma unroll
  for (int m = 0; m < 10; ++m) {
    const float4 qv = p[m];
    ev[m] = (kq&1) ? ((kq&2)? qv.w : qv.y) : ((kq&2)? qv.z : qv.x);
  }
  const int w = t >> 6, tl = t & 63;
  float mv[10];
  #pragma unroll
  for (int m = 0; m < 10; ++m) {
    mv[m] = ev[m];
    mv[m] = fmaxf(mv[m], __shfl_xor(mv[m], 4));
    mv[m] = fmaxf(mv[m], __shfl_xor(mv[m], 8));
    mv[m] = fmaxf(mv[m], __shfl_xor(mv[m], 16));
    mv[m] = fmaxf(mv[m], __shfl_xor(mv[m], 32));
  }
  if (tl < 4) {
    #pragma unroll
    for (int m = 0; m < 10; ++m) sredm[w*40 + 4*m + kq] = mv[m];
  }
  __syncthreads();
  if (t < 40)
    redm[t] = fmaxf(fmaxf(sredm[t], sredm[40+t]), fmaxf(sredm[80+t], sredm[120+t]));
  __syncthreads();
  float es[10];
  #pragma unroll
  for (int m = 0; m < 10; ++m) {
    const float M = redm[4*m + kq];
    es[m] = __expf(ev[m]-M);
    es[m] += __shfl_xor(es[m], 4);
    es[m] += __shfl_xor(es[m], 8);
    es[m] += __shfl_xor(es[m], 16);
    es[m] += __shfl_xor(es[m], 32);
  }
  if (tl < 4) {
    #pragma unroll
    for (int m = 0; m < 10; ++m) sreds[w*40 + 4*m + kq] = es[m];
  }
  __syncthreads();
  if (t < 40) {
    PmB[t] = redm[t];
    PsB[t] = sreds[t]+sreds[40+t]+sreds[80+t]+sreds[120+t];
  }
}

// ---------------------------------------------------------------------------
// partials_lds (proven; block-contiguous Pm/Ps layout).
// ---------------------------------------------------------------------------
__device__ __forceinline__ void partials_lds(const float* p_l, const int t,
    float* sredm, float* sreds, float* redm,
    float* __restrict__ PmB, float* __restrict__ PsB) {
  const int r2 = t >> 2, kq = t & 3;
  const int w = t >> 6, tl = t & 63;
  float ev[10];
  #pragma unroll
  for (int m = 0; m < 10; ++m) ev[m] = p_l[r2*44 + 4*m + kq];
  float mv[10];
  #pragma unroll
  for (int m = 0; m < 10; ++m) {
    mv[m] = ev[m];
    mv[m] = fmaxf(mv[m], __shfl_xor(mv[m], 4));
    mv[m] = fmaxf(mv[m], __shfl_xor(mv[m], 8));
    mv[m] = fmaxf(mv[m], __shfl_xor(mv[m], 16));
    mv[m] = fmaxf(mv[m], __shfl_xor(mv[m], 32));
  }
  if (tl < 4) {
    #pragma unroll
    for (int m = 0; m < 10; ++m) sredm[w*40 + 4*m + kq] = mv[m];
  }
  __syncthreads();
  if (t < 40)
    redm[t] = fmaxf(fmaxf(sredm[t], sredm[40+t]), fmaxf(sredm[80+t], sredm[120+t]));
  __syncthreads();
  float es[10];
  #pragma unroll
  for (int m = 0; m < 10; ++m) {
    const float M = redm[4*m + kq];
    es[m] = __expf(ev[m]-M);
    es[m] += __shfl_xor(es[m], 4);
    es[m] += __shfl_xor(es[m], 8);
    es[m] += __shfl_xor(es[m], 16);
    es[m] += __shfl_xor(es[m], 32);
  }
  if (tl < 4) {
    #pragma unroll
    for (int m = 0; m < 10; ++m) sreds[w*40 + 4*m + kq] = es[m];
  }
  __syncthreads();
  if (t < 40) {
    PmB[t] = redm[t];
    PsB[t] = sreds[t]+sreds[40+t]+sreds[80+t]+sreds[120+t];
  }
}

// ---------------------------------------------------------------------------
// K2: y_p from fe, with INLINE fe-stats comb (reads PBf).
// ---------------------------------------------------------------------------
__global__ __launch_bounds__(256,4)
void k_yp3(const float* __restrict__ fe, const float* __restrict__ CW,
           const float* __restrict__ q, const double* __restrict__ PBf,
           float* __restrict__ yp) {
  __shared__ float in_t[64*64];
  __shared__ float Wl[64*32];
  __shared__ double fred[2];
  const int t = threadIdx.x;
  const int r0 = blockIdx.x * 64;
  #pragma unroll
  for (int s = 0; s < 4; ++s) {
    int f = (t + 256*s) * 4;
    int r = f >> 6, d = f & 63;
    float4 v = *(const float4*)(fe + (size_t)r0*FIN + f);
    *(float4*)(in_t + r*64 + (d ^ ((r & 7) * 8))) = v;
  }
  #pragma unroll
  for (int s = 0; s < 2; ++s) {
    int f = (t + 256*s) * 4;
    *(float4*)(Wl + f) = *(const float4*)(CW + CW_WV + f);
  }
  if (t < 64) {                          // inline comb (k_comb fe order)
    double c = (t < 20) ? PBf[2*t]   : 0.0;
    double d = (t < 20) ? PBf[2*t+1] : 0.0;
    #pragma unroll
    for (int off = 32; off > 0; off >>= 1) {
      c += __shfl_down(c, off);
      d += __shfl_down(d, off);
    }
    if (t == 0) { fred[0] = c; fred[1] = d; }
  }
  __syncthreads();
  const double cy = (double)YROWS * (double)C;
  const double myd = fred[0]/cy, vy = fred[1]/cy - myd*myd;
  const float ry = (float)(1.0/sqrt(vy + (double)EPS));
  const float mr = (float)myd * ry;
  const int r2 = t >> 2, kq = t & 3;
  const int swz = (r2 & 7) * 8;
  float acc[8] = {0,0,0,0,0,0,0,0};
  #pragma unroll
  for (int dc = 0; dc < 16; ++dc) {
    const int d = dc*4;
    const float4 a = *(const float4*)(in_t + r2*64 + (d ^ swz));
    { const float4 w0 = *(const float4*)(Wl + (d+0)*32 + kq*8);
      const float4 w1 = *(const float4*)(Wl + (d+0)*32 + kq*8 + 4); ACC8(acc, a.x, w0, w1); }
    { const float4 w0 = *(const float4*)(Wl + (d+1)*32 + kq*8);
      const float4 w1 = *(const float4*)(Wl + (d+1)*32 + kq*8 + 4); ACC8(acc, a.y, w0, w1); }
    { const float4 w0 = *(const float4*)(Wl + (d+2)*32 + kq*8);
      const float4 w1 = *(const float4*)(Wl + (d+2)*32 + kq*8 + 4); ACC8(acc, a.z, w0, w1); }
    { const float4 w0 = *(const float4*)(Wl + (d+3)*32 + kq*8);
      const float4 w1 = *(const float4*)(Wl + (d+3)*32 + kq*8 + 4); ACC8(acc, a.w, w0, w1); }
  }
  #pragma unroll
  for (int i = 0; i < 8; ++i) {
    const int k = kq*8 + i;
    const float typ = ry*(acc[i] + CW[CW_CBV+k]) - mr*CW[CW_CSV+k];
    float v = fmaxf(typ, 0.f);
    acc[i] = fmaxf(q[k]*v, 0.f);
  }
  *(float4*)(yp + (size_t)(r0+r2)*KK + kq*8)     = make_float4(acc[0],acc[1],acc[2],acc[3]);
  *(float4*)(yp + (size_t)(r0+r2)*KK + kq*8 + 4) = make_float4(acc[4],acc[5],acc[6],acc[7]);
}

// ---------------------------------------------------------------------------
// K3: layer-0 with INLINE nf-stats comb (2048 pairs, 8 strided per thread).
// 4-row blocked GEMM, streamed I-row -> p_l -> partials -> I write.
// ---------------------------------------------------------------------------
__global__ __launch_bounds__(256,4)
void k_I0c(const float* __restrict__ nf, const float* __restrict__ CW,
           const double* __restrict__ PBn, const float* __restrict__ yp,
           float* __restrict__ XU, float* __restrict__ GX,
           float* __restrict__ Pm, float* __restrict__ Ps,
           float* __restrict__ Ibf) {
  __shared__ __align__(16) float in_t[64*68];   // overlaid by p_l (64*44) later
  __shared__ __align__(16) float Wl[64*36];     // row d -> (d&15)*4 + (d>>4)
  __shared__ __align__(16) float ypj[40*40];
  __shared__ __align__(16) float wgl[64];
  __shared__ float sredm[160], sreds[160], redm[40];
  __shared__ double dred[8];
  float* p_l = in_t;
  const int t = threadIdx.x;
  const int bid = blockIdx.x;
  const int b = bid >> 6, blk = bid & 63;
  const size_t rowbase = (size_t)b*NPG + (size_t)blk*64;
  #pragma unroll
  for (int s = 0; s < 4; ++s) {
    int f = (t + 256*s) * 4;
    int r = f >> 6, d = f & 63;
    *(float4*)(in_t + r*68 + d) = *(const float4*)(nf + rowbase*FIN + f);
  }
  #pragma unroll
  for (int s = 0; s < 2; ++s) {
    int idx = t + 256*s;
    int d = idx >> 3, kc = idx & 7;
    *(float4*)(Wl + ((d&15)*4 + (d>>4))*36 + kc*4) = *(const float4*)(CW + CW_WU + idx*4);
  }
  for (int f4v = t; f4v < 320; f4v += 256) {
    int j = f4v >> 3, kc = f4v & 7;
    *(float4*)(ypj + j*40 + kc*4) = *(const float4*)(yp + (size_t)b*(JJ*KK) + f4v*4);
  }
  if (t < 64) wgl[t] = CW[CW_WG + t];
  {                                      // inline comb over 2048 pairs
    double a = 0.0, bb = 0.0;
    #pragma unroll
    for (int u = 0; u < 8; ++u) {
      a  += PBn[2*(t + 256*u)];
      bb += PBn[2*(t + 256*u) + 1];
    }
    #pragma unroll
    for (int off = 32; off > 0; off >>= 1) {
      a  += __shfl_down(a, off);
      bb += __shfl_down(bb, off);
    }
    if ((t & 63) == 0) { dred[(t>>6)*2] = a; dred[(t>>6)*2+1] = bb; }
  }
  __syncthreads();
  const double ST0 = dred[0]+dred[2]+dred[4]+dred[6];
  const double ST1 = dred[1]+dred[3]+dred[5]+dred[7];
  const double cx = (double)NTOT * (double)C;
  const double mx = ST0/cx, vx = ST1/cx - mx*mx;
  const float rx = (float)(1.0/sqrt(vx + (double)EPS));
  const float mr = (float)mx * rx;
  const int kq = t & 3, X = (t >> 2) & 3, rr = t >> 4;
  float acc[4][8];
  #pragma unroll
  for (int i=0;i<4;i++)
    #pragma unroll
    for (int u=0;u<8;u++) acc[i][u] = 0.f;
  #pragma unroll
  for (int dd = 0; dd < 4; ++dd) {
    float4 a4[4];
    #pragma unroll
    for (int i = 0; i < 4; ++i)
      a4[i] = *(const float4*)(in_t + (rr+16*i)*68 + X*16 + dd*4);
    #pragma unroll
    for (int qd = 0; qd < 4; ++qd) {
      const int lrow = (dd*4 + qd)*4 + X;
      const float4 w0 = *(const float4*)(Wl + lrow*36 + kq*8);
      const float4 w1 = *(const float4*)(Wl + lrow*36 + kq*8 + 4);
      #pragma unroll
      for (int i = 0; i < 4; ++i) {
        const float av = (qd==0)? a4[i].x : (qd==1)? a4[i].y : (qd==2)? a4[i].z : a4[i].w;
        ACC8(acc[i], av, w0, w1);
      }
    }
  }
  #pragma unroll
  for (int i = 0; i < 4; ++i)
    #pragma unroll
    for (int u = 0; u < 8; ++u) {
      acc[i][u] += __shfl_xor(acc[i][u], 4);
      acc[i][u] += __shfl_xor(acc[i][u], 8);
    }
  float gp[4];
  #pragma unroll
  for (int i = 0; i < 4; ++i) {
    const float4 a = *(const float4*)(in_t + (rr+16*i)*68 + X*16 + kq*4);
    const float4 w = *(const float4*)(wgl + X*16 + kq*4);
    gp[i] = dot4(a, w);
    gp[i] += __shfl_xor(gp[i], 1);
    gp[i] += __shfl_xor(gp[i], 2);
    gp[i] += __shfl_xor(gp[i], 4);
    gp[i] += __shfl_xor(gp[i], 8);
  }
  const float4 cb0 = *(const float4*)(CW + CW_CBU + kq*8);
  const float4 cb1 = *(const float4*)(CW + CW_CBU + kq*8 + 4);
  const float4 cu0 = *(const float4*)(CW + CW_CSU + kq*8);
  const float4 cu1 = *(const float4*)(CW + CW_CSU + kq*8 + 4);
  float xp[4][8];
  #pragma unroll
  for (int i = 0; i < 4; ++i) {
    acc[i][0] = rx*(acc[i][0] + cb0.x) - mr*cu0.x;
    acc[i][1] = rx*(acc[i][1] + cb0.y) - mr*cu0.y;
    acc[i][2] = rx*(acc[i][2] + cb0.z) - mr*cu0.z;
    acc[i][3] = rx*(acc[i][3] + cb0.w) - mr*cu0.w;
    acc[i][4] = rx*(acc[i][4] + cb1.x) - mr*cu1.x;
    acc[i][5] = rx*(acc[i][5] + cb1.y) - mr*cu1.y;
    acc[i][6] = rx*(acc[i][6] + cb1.z) - mr*cu1.z;
    acc[i][7] = rx*(acc[i][7] + cb1.w) - mr*cu1.w;
    #pragma unroll
    for (int u = 0; u < 8; ++u) xp[i][u] = fmaxf(acc[i][u], 0.f);
  }
  if (X == 0) {
    const float bG = CW[CW_SC], sG = CW[CW_SC+1];
    #pragma unroll
    for (int i = 0; i < 4; ++i) {
      const size_t row = rowbase + rr + 16*i;
      *(float4*)(XU + row*KK + kq*8)     = make_float4(acc[i][0],acc[i][1],acc[i][2],acc[i][3]);
      *(float4*)(XU + row*KK + kq*8 + 4) = make_float4(acc[i][4],acc[i][5],acc[i][6],acc[i][7]);
      if (kq == 0) GX[row] = rx*(gp[i] + bG) - mr*sG;
    }
  }
  __syncthreads();                       // all in_t reads done; overlay p_l
  #pragma unroll 2
  for (int jj = 0; jj < 10; ++jj) {
    const int j = X*10 + jj;
    const float4 y0 = *(const float4*)(ypj + j*40 + kq*8);
    const float4 y1 = *(const float4*)(ypj + j*40 + kq*8 + 4);
    float p4[4];
    #pragma unroll
    for (int i = 0; i < 4; ++i) p4[i] = dot8v(xp[i], y0, y1);
    #pragma unroll
    for (int i = 0; i < 4; ++i) {
      p4[i] += __shfl_xor(p4[i], 1);
      p4[i] += __shfl_xor(p4[i], 2);
    }
    if (kq == 0) {
      #pragma unroll
      for (int i = 0; i < 4; ++i)
        p_l[(rr+16*i)*44 + j] = p4[i];
    }
  }
  __syncthreads();
  partials_lds(p_l, t, sredm, sreds, redm,
               Pm + ((size_t)b*64 + blk)*40, Ps + ((size_t)b*64 + blk)*40);
  // I write (p_l untouched by partials_lds; coalesced f4)
  for (int f4v = t; f4v < 640; f4v += 256) {
    const int row = f4v / 10, jq = f4v - row*10;
    *(float4*)(Ibf + (rowbase+row)*JJ + jq*4) = *(const float4*)(p_l + row*44 + jq*4);
  }
}

// ---------------------------------------------------------------------------
// K4: fused layer update with INLINE softmax comb and transposed e-tile.
// (unchanged from round 10, proven)
// ---------------------------------------------------------------------------
template<int FINAL>
__global__ __launch_bounds__(256,4)
void k_fused7(float* __restrict__ XU, float* __restrict__ GX,
              float* __restrict__ Ibf,
              const float* __restrict__ yp, const float* __restrict__ CW,
              const float* __restrict__ gb,
              const float* __restrict__ PmIn, const float* __restrict__ PsIn,
              float* __restrict__ PmOut, float* __restrict__ PsOut,
              float* __restrict__ outp) {
  __shared__ float ypj[40*32];
  __shared__ float eT[40*65];            // e transposed; sred overlay later
  __shared__ float h_l[64*40];
  __shared__ float VUl[32*32];
  __shared__ float M_l[40], Si_l[40];
  __shared__ float vgxl[32], vghl[32];
  __shared__ float Mq[160], Sq[160];
  float* sredm = eT;
  float* sreds = eT + 160;
  float* redm  = eT + 320;
  const int t = threadIdx.x;
  const int bid = blockIdx.x;
  const int b = bid >> 6, blk = bid & 63;
  const size_t rowbase = (size_t)b*NPG + (size_t)blk*64;
  for (int f4v = t; f4v < 320; f4v += 256)
    *(float4*)(ypj + f4v*4) = *(const float4*)(yp + (size_t)b*(JJ*KK) + f4v*4);
  { const int f = t*4;
    *(float4*)(VUl + f) = *(const float4*)(CW + CW_VU + f); }
  if (t < 32) { vgxl[t] = CW[CW_VGX+t]; vghl[t] = CW[CW_VGH+t]; }
  // inline comb on block-contiguous partials
  const int j160 = t >> 2, q160 = t & 3;
  float pmv[16];
  if (t < 160) {
    float m = 0.f;
    #pragma unroll
    for (int u = 0; u < 16; ++u) {
      pmv[u] = PmIn[((size_t)b*64 + q160*16 + u)*40 + j160];
      m = fmaxf(m, pmv[u]);
    }
    Mq[t] = m;
  }
  __syncthreads();
  if (t < 40) M_l[t] = fmaxf(fmaxf(Mq[4*t], Mq[4*t+1]), fmaxf(Mq[4*t+2], Mq[4*t+3]));
  __syncthreads();
  if (t < 160) {
    const float M = M_l[j160];
    float s = 0.f;
    #pragma unroll
    for (int u = 0; u < 16; ++u)
      s += PsIn[((size_t)b*64 + q160*16 + u)*40 + j160] * __expf(pmv[u] - M);
    Sq[t] = s;
  }
  __syncthreads();
  if (t < 40) Si_l[t] = 1.f/(Sq[4*t] + Sq[4*t+1] + Sq[4*t+2] + Sq[4*t+3]);
  __syncthreads();
  // e staging from Ibf, TRANSPOSED: eT[j][row], stride 65
  for (int f4v = t; f4v < 640; f4v += 256) {
    const int row = f4v / 10, jq = f4v - row*10;
    const float4 iv = *(const float4*)(Ibf + (rowbase+row)*JJ + jq*4);
    eT[(jq*4+0)*65 + row] = __expf(iv.x - M_l[jq*4+0]) * Si_l[jq*4+0];
    eT[(jq*4+1)*65 + row] = __expf(iv.y - M_l[jq*4+1]) * Si_l[jq*4+1];
    eT[(jq*4+2)*65 + row] = __expf(iv.z - M_l[jq*4+2]) * Si_l[jq*4+2];
    eT[(jq*4+3)*65 + row] = __expf(iv.w - M_l[jq*4+3]) * Si_l[jq*4+3];
  }
  const int r2 = t >> 2, kq = t & 3;
  float xu[8];
  {
    const float4 x0 = *(const float4*)(XU + (rowbase+r2)*KK + kq*8);
    const float4 x1 = *(const float4*)(XU + (rowbase+r2)*KK + kq*8 + 4);
    xu[0]=x0.x; xu[1]=x0.y; xu[2]=x0.z; xu[3]=x0.w;
    xu[4]=x1.x; xu[5]=x1.y; xu[6]=x1.z; xu[7]=x1.w;
  }
  const float gx = GX[rowbase + r2];
  __syncthreads();
  // phase B: h[n][k] = relu(sum_j A[n][j]*yp[j][k]) — conflict-free e reads
  {
    const int rq = t >> 3, kc = t & 7;
    float4 h0 = make_float4(0.f,0.f,0.f,0.f), h1 = make_float4(0.f,0.f,0.f,0.f);
    #pragma unroll 4
    for (int j = 0; j < JJ; ++j) {
      const float4 yv = *(const float4*)(ypj + j*32 + kc*4);
      const float e0 = eT[j*65 + rq];
      const float e1 = eT[j*65 + rq + 32];
      h0.x += e0*yv.x; h0.y += e0*yv.y; h0.z += e0*yv.z; h0.w += e0*yv.w;
      h1.x += e1*yv.x; h1.y += e1*yv.y; h1.z += e1*yv.z; h1.w += e1*yv.w;
    }
    h0.x = fmaxf(h0.x,0.f); h0.y = fmaxf(h0.y,0.f); h0.z = fmaxf(h0.z,0.f); h0.w = fmaxf(h0.w,0.f);
    h1.x = fmaxf(h1.x,0.f); h1.y = fmaxf(h1.y,0.f); h1.z = fmaxf(h1.z,0.f); h1.w = fmaxf(h1.w,0.f);
    *(float4*)(h_l + rq*40 + kc*4) = h0;
    *(float4*)(h_l + (rq+32)*40 + kc*4) = h1;
  }
  __syncthreads();
  // phase C: hu = h@VU, gate, blend in K-space
  float hu[8] = {0,0,0,0,0,0,0,0};
  float gh2 = 0.f, ghx = 0.f;
  #pragma unroll 8
  for (int kp = 0; kp < KK; ++kp) {
    const float hv = h_l[r2*40 + kp];
    gh2 += hv * vghl[kp];
    ghx += hv * vgxl[kp];
    const float4 v0 = *(const float4*)(VUl + kp*32 + kq*8);
    const float4 v1 = *(const float4*)(VUl + kp*32 + kq*8 + 4);
    ACC8(hu, hv, v0, v1);
  }
  const float z = 1.f/(1.f + __expf(-(gx + gh2 + gb[0])));
  float xp[8];
  #pragma unroll
  for (int i = 0; i < 8; ++i) {
    xu[i] = (1.f - z)*xu[i] + z*hu[i];
    xp[i] = fmaxf(xu[i], 0.f);
  }
  if (!FINAL) {
    *(float4*)(XU + (rowbase+r2)*KK + kq*8)     = make_float4(xu[0],xu[1],xu[2],xu[3]);
    *(float4*)(XU + (rowbase+r2)*KK + kq*8 + 4) = make_float4(xu[4],xu[5],xu[6],xu[7]);
    if (kq == 0) GX[rowbase + r2] = (1.f - z)*gx + z*ghx;
  }
  // single irow on updated xp
  float4 p[10];
  irow_compute(ypj, xp, kq, p);
  if (FINAL) {
    float s = 0.f;
    #pragma unroll
    for (int m = 0; m < 10; ++m)
      s += p[m].x*p[m].x + p[m].y*p[m].y + p[m].z*p[m].z + p[m].w*p[m].w;
    if (kq == 0) outp[rowbase + r2] = 1.f/(1.f + __expf(-s));
    return;
  }
  // I write: lane kq stores m with (m&3)==kq (full row covered across 4 lanes)
  #pragma unroll
  for (int m = 0; m < 10; ++m)
    if ((m & 3) == kq)
      *(float4*)(Ibf + (rowbase+r2)*JJ + 4*m) = p[m];
  partials_out(p, t, kq, sredm, sreds, redm,
               PmOut + ((size_t)b*64 + blk)*40, PsOut + ((size_t)b*64 + blk)*40);
}

extern "C" void kernel_launch(void* const* d_in, const int* in_sizes, int n_in,
                              void* d_out, int out_size, void* d_ws, size_t ws_size,
                              hipStream_t stream) {
  const float* nf  = (const float*)d_in[0];
  const float* fe  = (const float*)d_in[1];
  const float* W   = (const float*)d_in[2];
  const float* bin = (const float*)d_in[3];
  const float* U   = (const float*)d_in[4];
  const float* V   = (const float*)d_in[5];
  const float* q   = (const float*)d_in[6];
  const float* gw  = (const float*)d_in[7];
  const float* gb  = (const float*)d_in[8];
  float* out = (float*)d_out;
  float* wf  = (float*)d_ws;

  float* XU  = wf + XU_OFF;
  float* GX  = wf + GX_OFF;
  float* YP  = wf + YP_OFF;
  float* PMa = wf + PMA_OFF;
  float* PSa = wf + PSA_OFF;
  float* PMb = wf + PMB_OFF;
  float* PSb = wf + PSB_OFF;
  float* CWp = wf + CWS_OFF;
  float* IBF = wf + IBF_OFF;
  double* PBn = (double*)(wf + PBN_OFF);
  double* PBf = (double*)(wf + PBF_OFF);

  k_pre<<<2, 256, 0, stream>>>(W, bin, U, V, gw, CWp);
  k_cov2<<<2068, 256, 0, stream>>>(nf, fe, CWp, PBn, PBf);
  k_yp3<<<YROWS/64, 256, 0, stream>>>(fe, CWp, q, PBf, YP);
  k_I0c<<<NTOT/64, 256, 0, stream>>>(nf, CWp, PBn, YP, XU, GX, PMa, PSa, IBF);
  k_fused7<0><<<NTOT/64, 256, 0, stream>>>(XU, GX, IBF, YP, CWp, gb, PMa, PSa, PMb, PSb, nullptr);
  k_fused7<1><<<NTOT/64, 256, 0, stream>>>(XU, GX, IBF, YP, CWp, gb, PMb, PSb, nullptr, nullptr, out);
}